// Round 3
// baseline (2677.342 us; speedup 1.0000x reference)
//
#include <hip/hip_runtime.h>

#define NB 8
#define CIN 3
#define N0 327680
#define N1 81920
#define N2 20480
#define KC 10
#define KA 4

__device__ __forceinline__ float sel4(int p, float a, float b, float c, float d) {
  float r = (p == 1) ? b : a;
  r = (p == 2) ? c : r;
  r = (p == 3) ? d : r;
  return r;
}

// ---- weights -> [k][c][o]; out = bias3 ----
__global__ __launch_bounds__(256) void kprep(
    const float* __restrict__ w1, const float* __restrict__ w2,
    const float* __restrict__ w3, const float* __restrict__ b3,
    float* __restrict__ w1t, float* __restrict__ w2t, float* __restrict__ w3t,
    float* __restrict__ out) {
  int t = blockIdx.x * 256 + threadIdx.x;
  if (t < 480)  { int o = t & 15, c = (t >> 4) % 3, k = t / 48;
                  w1t[t] = w1[(o * 3 + c) * KC + k]; }
  if (t < 5120) { int o = t & 31, c = (t >> 5) & 15, k = t >> 9;
                  w2t[t] = w2[(o * 16 + c) * KC + k]; }
  if (t < 3200) { int o = t % 10, r = t / 10, c = r & 31, k = r >> 5;
                  w3t[t] = w3[(o * 32 + c) * KC + k]; }
  if (t < 80)   out[t] = b3[t % 10];
}

// ---- x [b][c][n] -> xT [b][n][S] (S=4 padded for dwordx4 gathers) ----
template<int S>
__global__ __launch_bounds__(256) void ktransx(
    const float* __restrict__ x, float* __restrict__ xT) {
  int blk = blockIdx.x;
  int b = blk / (N0 / 256);
  int n = (blk % (N0 / 256)) * 256 + threadIdx.x;
  size_t src = (size_t)b * CIN * N0 + n;
  float v0 = x[src], v1 = x[src + N0], v2 = x[src + 2 * (size_t)N0];
  if (S == 4) {
    float4 w = {v0, v1, v2, 0.f};
    *(float4*)(xT + ((size_t)b * N0 + n) * 4) = w;
  } else {
    size_t dst = ((size_t)b * N0 + n) * 3;
    xT[dst] = v0; xT[dst + 1] = v1; xT[dst + 2] = v2;
  }
}

// ---- fused, pre-scaled index tables: [j][p][12] (padded for int4 loads) ----
__global__ __launch_bounds__(256) void kfidx(
    const int* __restrict__ conv_t0, const int* __restrict__ conv_t1,
    const int* __restrict__ adj0, const int* __restrict__ adj1,
    const int* __restrict__ pool0, const int* __restrict__ pool1,
    int* __restrict__ fidx0, int* __restrict__ fidx1, int xstride) {
  int j = blockIdx.x * 256 + threadIdx.x;
  int pj = pool0[j];
#pragma unroll
  for (int p = 0; p < KA; ++p) {
    int pos = adj0[pj * KA + p];
#pragma unroll
    for (int k = 0; k < KC; ++k)
      fidx0[(size_t)j * 48 + p * 12 + k] = conv_t0[pos * KC + k] * xstride;
  }
  if (j < N2) {
    int qj = pool1[j];
#pragma unroll
    for (int p = 0; p < KA; ++p) {
      int pos = adj1[qj * KA + p];
#pragma unroll
      for (int k = 0; k < KC; ++k)
        fidx1[(size_t)j * 48 + p * 12 + k] = conv_t1[pos * KC + k] * 16;
    }
  }
}

// ---- conv1 (3->16) + maxpool0, thread = (b,j,p) ----
template<int S>
__global__ __launch_bounds__(256) void k1(
    const float* __restrict__ xT, const int* __restrict__ fidx0,
    const float* __restrict__ wt, const float* __restrict__ b1,
    float* __restrict__ h2) {
  int blk = blockIdx.x;
  int b = blk & 7;                              // XCD-pinned batch
  int slot = (blk >> 3) * 256 + threadIdx.x;
  int j = slot >> 2, p = slot & 3;
  const int* fi = fidx0 + (size_t)j * 48 + p * 12;
  int4 i0 = ((const int4*)fi)[0];
  int4 i1 = ((const int4*)fi)[1];
  int4 i2 = ((const int4*)fi)[2];
  int idx[10] = {i0.x, i0.y, i0.z, i0.w, i1.x, i1.y, i1.z, i1.w, i2.x, i2.y};
  const float* xb = xT + (size_t)b * N0 * S;
  float acc[16];
#pragma unroll
  for (int o = 0; o < 16; ++o) acc[o] = 0.f;
#pragma unroll
  for (int k = 0; k < KC; ++k) {
    float v0, v1, v2;
    if (S == 4) {
      float4 v = *(const float4*)(xb + idx[k]);
      v0 = v.x; v1 = v.y; v2 = v.z;
    } else {
      const float* px = xb + idx[k];
      v0 = px[0]; v1 = px[1]; v2 = px[2];
    }
    const float* wk = wt + k * 48;
#pragma unroll
    for (int o = 0; o < 16; ++o)
      acc[o] = fmaf(v0, wk[o], fmaf(v1, wk[16 + o], fmaf(v2, wk[32 + o], acc[o])));
  }
#pragma unroll
  for (int o = 0; o < 16; ++o) acc[o] += b1[o];   // bias before max: commutes
#pragma unroll
  for (int off = 1; off < 4; off <<= 1)
#pragma unroll
    for (int o = 0; o < 16; ++o)
      acc[o] = fmaxf(acc[o], __shfl_xor(acc[o], off));
  float4 r;
  r.x = sel4(p, acc[0], acc[4], acc[8],  acc[12]);
  r.y = sel4(p, acc[1], acc[5], acc[9],  acc[13]);
  r.z = sel4(p, acc[2], acc[6], acc[10], acc[14]);
  r.w = sel4(p, acc[3], acc[7], acc[11], acc[15]);
  *(float4*)(h2 + ((size_t)b * N1 + j) * 16 + p * 4) = r;
}

// ---- conv2 (16->32) + maxpool1, thread = (b,j,p) ----
__global__ __launch_bounds__(256) void k2(
    const float* __restrict__ h2, const int* __restrict__ fidx1,
    const float* __restrict__ wt, const float* __restrict__ b2,
    float* __restrict__ h3) {
  int blk = blockIdx.x;
  int b = blk & 7;
  int slot = (blk >> 3) * 256 + threadIdx.x;
  int j = slot >> 2, p = slot & 3;
  const int* fi = fidx1 + (size_t)j * 48 + p * 12;
  int4 i0 = ((const int4*)fi)[0];
  int4 i1 = ((const int4*)fi)[1];
  int4 i2 = ((const int4*)fi)[2];
  int idx[10] = {i0.x, i0.y, i0.z, i0.w, i1.x, i1.y, i1.z, i1.w, i2.x, i2.y};
  const float* hb = h2 + (size_t)b * N1 * 16;
  float acc[32];
#pragma unroll
  for (int o = 0; o < 32; ++o) acc[o] = 0.f;
#pragma unroll
  for (int k = 0; k < KC; ++k) {
    const float4* ph = (const float4*)(hb + idx[k]);
    float4 va = ph[0], vb = ph[1], vc = ph[2], vd = ph[3];
    float v[16] = {va.x, va.y, va.z, va.w, vb.x, vb.y, vb.z, vb.w,
                   vc.x, vc.y, vc.z, vc.w, vd.x, vd.y, vd.z, vd.w};
    const float* wk = wt + k * 512;
#pragma unroll
    for (int c = 0; c < 16; ++c)
#pragma unroll
      for (int o = 0; o < 32; ++o)
        acc[o] = fmaf(v[c], wk[c * 32 + o], acc[o]);
  }
#pragma unroll
  for (int o = 0; o < 32; ++o) acc[o] += b2[o];
#pragma unroll
  for (int off = 1; off < 4; off <<= 1)
#pragma unroll
    for (int o = 0; o < 32; ++o)
      acc[o] = fmaxf(acc[o], __shfl_xor(acc[o], off));
  float4 r0, r1;
  r0.x = sel4(p, acc[0], acc[8],  acc[16], acc[24]);
  r0.y = sel4(p, acc[1], acc[9],  acc[17], acc[25]);
  r0.z = sel4(p, acc[2], acc[10], acc[18], acc[26]);
  r0.w = sel4(p, acc[3], acc[11], acc[19], acc[27]);
  r1.x = sel4(p, acc[4], acc[12], acc[20], acc[28]);
  r1.y = sel4(p, acc[5], acc[13], acc[21], acc[29]);
  r1.z = sel4(p, acc[6], acc[14], acc[22], acc[30]);
  r1.w = sel4(p, acc[7], acc[15], acc[23], acc[31]);
  float* dst = h3 + ((size_t)b * N2 + j) * 32 + p * 8;
  *(float4*)dst = r0;
  *(float4*)(dst + 4) = r1;
}

// ---- conv3 (32->10) + mean, thread = (b,j,c-half) ----
__global__ __launch_bounds__(256) void k3(
    const float* __restrict__ h3, const int* __restrict__ conv_t2,
    const float* __restrict__ wt, float* __restrict__ out) {
  int blk = blockIdx.x;
  int b = blk & 7;
  int slot = (blk >> 3) * 256 + threadIdx.x;
  int j = slot >> 1, ch = slot & 1;
  int idx[KC];
#pragma unroll
  for (int k = 0; k < KC; ++k) idx[k] = conv_t2[(size_t)j * KC + k] * 32 + ch * 16;
  const float* hb = h3 + (size_t)b * N2 * 32;
  float acc[10];
#pragma unroll
  for (int o = 0; o < 10; ++o) acc[o] = 0.f;
#pragma unroll
  for (int k = 0; k < KC; ++k) {
    const float4* ph = (const float4*)(hb + idx[k]);
    float4 va = ph[0], vb = ph[1], vc = ph[2], vd = ph[3];
    float v[16] = {va.x, va.y, va.z, va.w, vb.x, vb.y, vb.z, vb.w,
                   vc.x, vc.y, vc.z, vc.w, vd.x, vd.y, vd.z, vd.w};
    const float* wk = wt + k * 320 + ch * 160;
#pragma unroll
    for (int c = 0; c < 16; ++c)
#pragma unroll
      for (int o = 0; o < 10; ++o)
        acc[o] = fmaf(v[c], wk[c * 10 + o], acc[o]);
  }
#pragma unroll
  for (int o = 0; o < 10; ++o) {
    float s = acc[o];
#pragma unroll
    for (int off = 1; off < 64; off <<= 1) s += __shfl_xor(s, off);
    if ((threadIdx.x & 63) == 0) atomicAdd(&out[b * 10 + o], s * (1.0f / N2));
  }
}

extern "C" void kernel_launch(void* const* d_in, const int* in_sizes, int n_in,
                              void* d_out, int out_size, void* d_ws, size_t ws_size,
                              hipStream_t stream) {
  const float* x       = (const float*)d_in[0];
  const int*   conv_t0 = (const int*)d_in[1];
  const int*   conv_t1 = (const int*)d_in[2];
  const int*   conv_t2 = (const int*)d_in[3];
  const int*   adj0    = (const int*)d_in[4];
  const int*   adj1    = (const int*)d_in[5];
  const int*   pool0   = (const int*)d_in[6];
  const int*   pool1   = (const int*)d_in[7];
  const float* w1      = (const float*)d_in[8];
  const float* b1      = (const float*)d_in[9];
  const float* w2      = (const float*)d_in[10];
  const float* b2      = (const float*)d_in[11];
  const float* w3      = (const float*)d_in[12];
  const float* b3      = (const float*)d_in[13];
  float* out  = (float*)d_out;
  float* wsf  = (float*)d_ws;

  // words: xT(pad4)=10,485,760  h2=10,485,760  fidx0=3,932,160  fidx1=983,040  w=8,800
  const bool pad4 = ws_size >= (size_t)25895520 * 4;
  const size_t xtw = pad4 ? (size_t)NB * N0 * 4 : (size_t)NB * N0 * 3;
  float* xT    = wsf;                       // dead after k1
  float* h3b   = wsf;                       // aliases xT (5.2M words < xtw)
  float* h2b   = wsf + xtw;
  int*   fidx0 = (int*)(h2b + (size_t)NB * N1 * 16);
  int*   fidx1 = fidx0 + (size_t)N1 * 48;
  float* w1t   = (float*)(fidx1 + (size_t)N2 * 48);
  float* w2t   = w1t + 480;
  float* w3t   = w2t + 5120;

  kprep<<<20, 256, 0, stream>>>(w1, w2, w3, b3, w1t, w2t, w3t, out);
  if (pad4) ktransx<4><<<NB * (N0 / 256), 256, 0, stream>>>(x, xT);
  else      ktransx<3><<<NB * (N0 / 256), 256, 0, stream>>>(x, xT);
  kfidx<<<N1 / 256, 256, 0, stream>>>(conv_t0, conv_t1, adj0, adj1, pool0, pool1,
                                      fidx0, fidx1, pad4 ? 4 : 3);
  if (pad4) k1<4><<<NB * (N1 * 4 / 256), 256, 0, stream>>>(xT, fidx0, w1t, b1, h2b);
  else      k1<3><<<NB * (N1 * 4 / 256), 256, 0, stream>>>(xT, fidx0, w1t, b1, h2b);
  k2<<<NB * (N2 * 4 / 256), 256, 0, stream>>>(h2b, fidx1, w2t, b2, h3b);
  k3<<<NB * (N2 * 2 / 256), 256, 0, stream>>>(h3b, conv_t2, w3t, out);
}

// Round 4
// 412.797 us; speedup vs baseline: 6.4859x; 6.4859x over previous
//
#include <hip/hip_runtime.h>

#define NB 8
#define CIN 3
#define N0 327680
#define N1 81920
#define N2 20480
#define KC 10
#define KA 4

__device__ __forceinline__ float sel4(int p, float a, float b, float c, float d) {
  float r = (p == 1) ? b : a;
  r = (p == 2) ? c : r;
  r = (p == 3) ? d : r;
  return r;
}

// ---- weights -> [k][c][o]; out = bias3 ----
__global__ __launch_bounds__(256) void kprep(
    const float* __restrict__ w1, const float* __restrict__ w2,
    const float* __restrict__ w3, const float* __restrict__ b3,
    float* __restrict__ w1t, float* __restrict__ w2t, float* __restrict__ w3t,
    float* __restrict__ out) {
  int t = blockIdx.x * 256 + threadIdx.x;
  if (t < 480)  { int o = t & 15, c = (t >> 4) % 3, k = t / 48;
                  w1t[t] = w1[(o * 3 + c) * KC + k]; }
  if (t < 5120) { int o = t & 31, c = (t >> 5) & 15, k = t >> 9;
                  w2t[t] = w2[(o * 16 + c) * KC + k]; }
  if (t < 3200) { int o = t % 10, r = t / 10, c = r & 31, k = r >> 5;
                  w3t[t] = w3[(o * 32 + c) * KC + k]; }
  if (t < 80)   out[t] = b3[t % 10];
}

// ---- x [b][c][n] -> xT [b][n][S] (S=4 padded for dwordx4 gathers) ----
template<int S>
__global__ __launch_bounds__(256) void ktransx(
    const float* __restrict__ x, float* __restrict__ xT) {
  int blk = blockIdx.x;
  int b = blk / (N0 / 256);
  int n = (blk % (N0 / 256)) * 256 + threadIdx.x;
  size_t src = (size_t)b * CIN * N0 + n;
  float v0 = x[src], v1 = x[src + N0], v2 = x[src + 2 * (size_t)N0];
  if (S == 4) {
    float4 w = {v0, v1, v2, 0.f};
    *(float4*)(xT + ((size_t)b * N0 + n) * 4) = w;
  } else {
    size_t dst = ((size_t)b * N0 + n) * 3;
    xT[dst] = v0; xT[dst + 1] = v1; xT[dst + 2] = v2;
  }
}

// ---- fused, pre-scaled index tables: [j][p][12]; thread = (j,p) ----
__global__ __launch_bounds__(256) void kfidx(
    const int* __restrict__ conv_t0, const int* __restrict__ conv_t1,
    const int* __restrict__ adj0, const int* __restrict__ adj1,
    const int* __restrict__ pool0, const int* __restrict__ pool1,
    int* __restrict__ fidx0, int* __restrict__ fidx1, int xstride) {
  int t = blockIdx.x * 256 + threadIdx.x;       // N1*4 threads
  int j = t >> 2, p = t & 3;
  int pj = pool0[j];
  int pos = adj0[pj * KA + p];
#pragma unroll
  for (int k = 0; k < KC; ++k)
    fidx0[(size_t)j * 48 + p * 12 + k] = conv_t0[pos * KC + k] * xstride;
  if (j < N2) {
    int qj = pool1[j];
    int qos = adj1[qj * KA + p];
#pragma unroll
    for (int k = 0; k < KC; ++k)
      fidx1[(size_t)j * 48 + p * 12 + k] = conv_t1[qos * KC + k] * 16;
  }
}

// ---- conv1 (3->16) + maxpool0, thread = (b,j,p) ----
template<int S>
__global__ __launch_bounds__(256) void k1(
    const float* __restrict__ xT, const int* __restrict__ fidx0,
    const float* __restrict__ wt, const float* __restrict__ b1,
    float* __restrict__ h2) {
  int blk = blockIdx.x;
  int b = blk & 7;                              // XCD-pinned batch
  int slot = (blk >> 3) * 256 + threadIdx.x;
  int j = slot >> 2, p = slot & 3;
  const int* fi = fidx0 + (size_t)j * 48 + p * 12;
  int4 i0 = ((const int4*)fi)[0];
  int4 i1 = ((const int4*)fi)[1];
  int4 i2 = ((const int4*)fi)[2];
  int idx[10] = {i0.x, i0.y, i0.z, i0.w, i1.x, i1.y, i1.z, i1.w, i2.x, i2.y};
  const float* xb = xT + (size_t)b * N0 * S;
  float acc[16];
#pragma unroll
  for (int o = 0; o < 16; ++o) acc[o] = 0.f;
#pragma unroll
  for (int k = 0; k < KC; ++k) {
    float v0, v1, v2;
    if (S == 4) {
      float4 v = *(const float4*)(xb + idx[k]);
      v0 = v.x; v1 = v.y; v2 = v.z;
    } else {
      const float* px = xb + idx[k];
      v0 = px[0]; v1 = px[1]; v2 = px[2];
    }
    const float* wk = wt + k * 48;
#pragma unroll
    for (int o = 0; o < 16; ++o)
      acc[o] = fmaf(v0, wk[o], fmaf(v1, wk[16 + o], fmaf(v2, wk[32 + o], acc[o])));
  }
#pragma unroll
  for (int o = 0; o < 16; ++o) acc[o] += b1[o];   // bias before max: commutes
#pragma unroll
  for (int off = 1; off < 4; off <<= 1)
#pragma unroll
    for (int o = 0; o < 16; ++o)
      acc[o] = fmaxf(acc[o], __shfl_xor(acc[o], off));
  float4 r;
  r.x = sel4(p, acc[0], acc[4], acc[8],  acc[12]);
  r.y = sel4(p, acc[1], acc[5], acc[9],  acc[13]);
  r.z = sel4(p, acc[2], acc[6], acc[10], acc[14]);
  r.w = sel4(p, acc[3], acc[7], acc[11], acc[15]);
  *(float4*)(h2 + ((size_t)b * N1 + j) * 16 + p * 4) = r;
}

// ---- conv2 (16->32) + maxpool1, thread = (b,j,p) ----
__global__ __launch_bounds__(256) void k2(
    const float* __restrict__ h2, const int* __restrict__ fidx1,
    const float* __restrict__ wt, const float* __restrict__ b2,
    float* __restrict__ h3) {
  int blk = blockIdx.x;
  int b = blk & 7;
  int slot = (blk >> 3) * 256 + threadIdx.x;
  int j = slot >> 2, p = slot & 3;
  const int* fi = fidx1 + (size_t)j * 48 + p * 12;
  int4 i0 = ((const int4*)fi)[0];
  int4 i1 = ((const int4*)fi)[1];
  int4 i2 = ((const int4*)fi)[2];
  int idx[10] = {i0.x, i0.y, i0.z, i0.w, i1.x, i1.y, i1.z, i1.w, i2.x, i2.y};
  const float* hb = h2 + (size_t)b * N1 * 16;
  float acc[32];
#pragma unroll
  for (int o = 0; o < 32; ++o) acc[o] = 0.f;
#pragma unroll
  for (int k = 0; k < KC; ++k) {
    const float4* ph = (const float4*)(hb + idx[k]);
    float4 va = ph[0], vb = ph[1], vc = ph[2], vd = ph[3];
    float v[16] = {va.x, va.y, va.z, va.w, vb.x, vb.y, vb.z, vb.w,
                   vc.x, vc.y, vc.z, vc.w, vd.x, vd.y, vd.z, vd.w};
    const float* wk = wt + k * 512;
#pragma unroll
    for (int c = 0; c < 16; ++c)
#pragma unroll
      for (int o = 0; o < 32; ++o)
        acc[o] = fmaf(v[c], wk[c * 32 + o], acc[o]);
  }
#pragma unroll
  for (int o = 0; o < 32; ++o) acc[o] += b2[o];
#pragma unroll
  for (int off = 1; off < 4; off <<= 1)
#pragma unroll
    for (int o = 0; o < 32; ++o)
      acc[o] = fmaxf(acc[o], __shfl_xor(acc[o], off));
  float4 r0, r1;
  r0.x = sel4(p, acc[0], acc[8],  acc[16], acc[24]);
  r0.y = sel4(p, acc[1], acc[9],  acc[17], acc[25]);
  r0.z = sel4(p, acc[2], acc[10], acc[18], acc[26]);
  r0.w = sel4(p, acc[3], acc[11], acc[19], acc[27]);
  r1.x = sel4(p, acc[4], acc[12], acc[20], acc[28]);
  r1.y = sel4(p, acc[5], acc[13], acc[21], acc[29]);
  r1.z = sel4(p, acc[6], acc[14], acc[22], acc[30]);
  r1.w = sel4(p, acc[7], acc[15], acc[23], acc[31]);
  float* dst = h3 + ((size_t)b * N2 + j) * 32 + p * 8;
  *(float4*)dst = r0;
  *(float4*)(dst + 4) = r1;
}

// ---- conv3 (32->10) + mean, thread = (b,j); CH = compile-time channel half ----
template<int CH>
__global__ __launch_bounds__(256) void k3(
    const float* __restrict__ h3, const int* __restrict__ conv_t2,
    const float* __restrict__ wt, float* __restrict__ out) {
  int blk = blockIdx.x;
  int b = blk & 7;
  int j = (blk >> 3) * 256 + threadIdx.x;
  int idx[KC];
#pragma unroll
  for (int k = 0; k < KC; ++k) idx[k] = conv_t2[(size_t)j * KC + k] * 32 + CH * 16;
  const float* hb = h3 + (size_t)b * N2 * 32;
  float acc[10];
#pragma unroll
  for (int o = 0; o < 10; ++o) acc[o] = 0.f;
#pragma unroll
  for (int k = 0; k < KC; ++k) {
    const float4* ph = (const float4*)(hb + idx[k]);
#pragma unroll
    for (int q = 0; q < 4; ++q) {
      float4 t = ph[q];
      // weight index fully compile-time -> s_load, no spill
#pragma unroll
      for (int o = 0; o < 10; ++o)
        acc[o] = fmaf(t.x, wt[k * 320 + (CH * 16 + q * 4 + 0) * 10 + o],
                 fmaf(t.y, wt[k * 320 + (CH * 16 + q * 4 + 1) * 10 + o],
                 fmaf(t.z, wt[k * 320 + (CH * 16 + q * 4 + 2) * 10 + o],
                 fmaf(t.w, wt[k * 320 + (CH * 16 + q * 4 + 3) * 10 + o], acc[o]))));
    }
  }
#pragma unroll
  for (int off = 1; off < 64; off <<= 1)
#pragma unroll
    for (int o = 0; o < 10; ++o) acc[o] += __shfl_xor(acc[o], off);
  int lane = threadIdx.x & 63;
  float s = acc[0];
  s = (lane == 1) ? acc[1] : s;
  s = (lane == 2) ? acc[2] : s;
  s = (lane == 3) ? acc[3] : s;
  s = (lane == 4) ? acc[4] : s;
  s = (lane == 5) ? acc[5] : s;
  s = (lane == 6) ? acc[6] : s;
  s = (lane == 7) ? acc[7] : s;
  s = (lane == 8) ? acc[8] : s;
  s = (lane == 9) ? acc[9] : s;
  if (lane < 10) atomicAdd(&out[b * 10 + lane], s * (1.0f / N2));
}

extern "C" void kernel_launch(void* const* d_in, const int* in_sizes, int n_in,
                              void* d_out, int out_size, void* d_ws, size_t ws_size,
                              hipStream_t stream) {
  const float* x       = (const float*)d_in[0];
  const int*   conv_t0 = (const int*)d_in[1];
  const int*   conv_t1 = (const int*)d_in[2];
  const int*   conv_t2 = (const int*)d_in[3];
  const int*   adj0    = (const int*)d_in[4];
  const int*   adj1    = (const int*)d_in[5];
  const int*   pool0   = (const int*)d_in[6];
  const int*   pool1   = (const int*)d_in[7];
  const float* w1      = (const float*)d_in[8];
  const float* b1      = (const float*)d_in[9];
  const float* w2      = (const float*)d_in[10];
  const float* b2      = (const float*)d_in[11];
  const float* w3      = (const float*)d_in[12];
  const float* b3      = (const float*)d_in[13];
  float* out  = (float*)d_out;
  float* wsf  = (float*)d_ws;

  // words: xT(pad4)=10,485,760  h2=10,485,760  fidx0=3,932,160  fidx1=983,040  w=8,800
  const bool pad4 = ws_size >= (size_t)25895520 * 4;
  const size_t xtw = pad4 ? (size_t)NB * N0 * 4 : (size_t)NB * N0 * 3;
  float* xT    = wsf;                       // dead after k1
  float* h3b   = wsf;                       // aliases xT (5.2M words < xtw)
  float* h2b   = wsf + xtw;
  int*   fidx0 = (int*)(h2b + (size_t)NB * N1 * 16);
  int*   fidx1 = fidx0 + (size_t)N1 * 48;
  float* w1t   = (float*)(fidx1 + (size_t)N2 * 48);
  float* w2t   = w1t + 480;
  float* w3t   = w2t + 5120;

  kprep<<<20, 256, 0, stream>>>(w1, w2, w3, b3, w1t, w2t, w3t, out);
  if (pad4) ktransx<4><<<NB * (N0 / 256), 256, 0, stream>>>(x, xT);
  else      ktransx<3><<<NB * (N0 / 256), 256, 0, stream>>>(x, xT);
  kfidx<<<N1 * 4 / 256, 256, 0, stream>>>(conv_t0, conv_t1, adj0, adj1, pool0, pool1,
                                          fidx0, fidx1, pad4 ? 4 : 3);
  if (pad4) k1<4><<<NB * (N1 * 4 / 256), 256, 0, stream>>>(xT, fidx0, w1t, b1, h2b);
  else      k1<3><<<NB * (N1 * 4 / 256), 256, 0, stream>>>(xT, fidx0, w1t, b1, h2b);
  k2<<<NB * (N2 * 4 / 256), 256, 0, stream>>>(h2b, fidx1, w2t, b2, h3b);
  k3<0><<<NB * (N2 / 256), 256, 0, stream>>>(h3b, conv_t2, w3t, out);
  k3<1><<<NB * (N2 / 256), 256, 0, stream>>>(h3b, conv_t2, w3t, out);
}

// Round 5
// 375.533 us; speedup vs baseline: 7.1294x; 1.0992x over previous
//
#include <hip/hip_runtime.h>

#define NB 8
#define CIN 3
#define N0 327680
#define N1 81920
#define N2 20480
#define KC 10
#define KA 4

__device__ __forceinline__ unsigned f2bf(float f) {          // RNE float->bf16
  unsigned u = __float_as_uint(f);
  return (u + 0x7FFFu + ((u >> 16) & 1u)) >> 16;
}
__device__ __forceinline__ float bfLo(unsigned w) { return __uint_as_float(w << 16); }
__device__ __forceinline__ float bfHi(unsigned w) { return __uint_as_float(w & 0xFFFF0000u); }

__device__ __forceinline__ float sel4(int p, float a, float b, float c, float d) {
  float r = (p == 1) ? b : a;
  r = (p == 2) ? c : r;
  r = (p == 3) ? d : r;
  return r;
}

// ---- weights -> [k][c][o]; out = bias3 ----
__global__ __launch_bounds__(256) void kprep(
    const float* __restrict__ w1, const float* __restrict__ w2,
    const float* __restrict__ w3, const float* __restrict__ b3,
    float* __restrict__ w1t, float* __restrict__ w2t, float* __restrict__ w3t,
    float* __restrict__ out) {
  int t = blockIdx.x * 256 + threadIdx.x;
  if (t < 480)  { int o = t & 15, c = (t >> 4) % 3, k = t / 48;
                  w1t[t] = w1[(o * 3 + c) * KC + k]; }
  if (t < 5120) { int o = t & 31, c = (t >> 5) & 15, k = t >> 9;
                  w2t[t] = w2[(o * 16 + c) * KC + k]; }
  if (t < 3200) { int o = t % 10, r = t / 10, c = r & 31, k = r >> 5;
                  w3t[t] = w3[(o * 32 + c) * KC + k]; }
  if (t < 80)   out[t] = b3[t % 10];
}

// ---- x [b][c][n] -> xT bf16 [b][n][4] (8 B/position, 2.62 MB/batch) ----
__global__ __launch_bounds__(256) void ktransx(
    const float* __restrict__ x, ushort4* __restrict__ xT) {
  int blk = blockIdx.x;
  int b = blk / (N0 / 256);
  int n = (blk % (N0 / 256)) * 256 + threadIdx.x;
  size_t src = (size_t)b * CIN * N0 + n;
  ushort4 w;
  w.x = (unsigned short)f2bf(x[src]);
  w.y = (unsigned short)f2bf(x[src + N0]);
  w.z = (unsigned short)f2bf(x[src + 2 * (size_t)N0]);
  w.w = 0;
  xT[(size_t)b * N0 + n] = w;
}

// ---- fused index tables [j][p][12]; fidx0 in uint2 units, fidx1 in uint4 units ----
__global__ __launch_bounds__(256) void kfidx(
    const int* __restrict__ conv_t0, const int* __restrict__ conv_t1,
    const int* __restrict__ adj0, const int* __restrict__ adj1,
    const int* __restrict__ pool0, const int* __restrict__ pool1,
    int* __restrict__ fidx0, int* __restrict__ fidx1) {
  int t = blockIdx.x * 256 + threadIdx.x;       // N1*4 threads
  int j = t >> 2, p = t & 3;
  int pj = pool0[j];
  int pos = adj0[pj * KA + p];
#pragma unroll
  for (int k = 0; k < KC; ++k)
    fidx0[(size_t)j * 48 + p * 12 + k] = conv_t0[pos * KC + k];        // uint2 index
  if (j < N2) {
    int qj = pool1[j];
    int qos = adj1[qj * KA + p];
#pragma unroll
    for (int k = 0; k < KC; ++k)
      fidx1[(size_t)j * 48 + p * 12 + k] = conv_t1[qos * KC + k] * 2;  // uint4 index
  }
}

// ---- conv1 (3->16) + maxpool0, thread = (b,j,p); bf16 in, fp32 math, bf16 out ----
__global__ __launch_bounds__(256) void k1(
    const uint2* __restrict__ xT, const int* __restrict__ fidx0,
    const float* __restrict__ wt, const float* __restrict__ b1,
    ushort4* __restrict__ h2) {
  int blk = blockIdx.x;
  int b = blk & 7;                              // XCD-pinned batch
  int slot = (blk >> 3) * 256 + threadIdx.x;
  int j = slot >> 2, p = slot & 3;
  const int* fi = fidx0 + (size_t)j * 48 + p * 12;
  int4 i0 = ((const int4*)fi)[0];
  int4 i1 = ((const int4*)fi)[1];
  int4 i2 = ((const int4*)fi)[2];
  int idx[10] = {i0.x, i0.y, i0.z, i0.w, i1.x, i1.y, i1.z, i1.w, i2.x, i2.y};
  const uint2* xb = xT + (size_t)b * N0;
  float acc[16];
#pragma unroll
  for (int o = 0; o < 16; ++o) acc[o] = 0.f;
#pragma unroll
  for (int k = 0; k < KC; ++k) {
    uint2 v = xb[idx[k]];
    float v0 = bfLo(v.x), v1 = bfHi(v.x), v2 = bfLo(v.y);
    const float* wk = wt + k * 48;
#pragma unroll
    for (int o = 0; o < 16; ++o)
      acc[o] = fmaf(v0, wk[o], fmaf(v1, wk[16 + o], fmaf(v2, wk[32 + o], acc[o])));
  }
#pragma unroll
  for (int o = 0; o < 16; ++o) acc[o] += b1[o];   // bias before max: commutes
#pragma unroll
  for (int off = 1; off < 4; off <<= 1)
#pragma unroll
    for (int o = 0; o < 16; ++o)
      acc[o] = fmaxf(acc[o], __shfl_xor(acc[o], off));
  ushort4 r;
  r.x = (unsigned short)f2bf(sel4(p, acc[0], acc[4], acc[8],  acc[12]));
  r.y = (unsigned short)f2bf(sel4(p, acc[1], acc[5], acc[9],  acc[13]));
  r.z = (unsigned short)f2bf(sel4(p, acc[2], acc[6], acc[10], acc[14]));
  r.w = (unsigned short)f2bf(sel4(p, acc[3], acc[7], acc[11], acc[15]));
  h2[((size_t)b * N1 + j) * 4 + p] = r;
}

// ---- conv2 (16->32) + maxpool1, thread = (b,j,p); bf16 in, fp32 out ----
__global__ __launch_bounds__(256) void k2(
    const uint4* __restrict__ h2, const int* __restrict__ fidx1,
    const float* __restrict__ wt, const float* __restrict__ b2,
    float* __restrict__ h3) {
  int blk = blockIdx.x;
  int b = blk & 7;
  int slot = (blk >> 3) * 256 + threadIdx.x;
  int j = slot >> 2, p = slot & 3;
  const int* fi = fidx1 + (size_t)j * 48 + p * 12;
  int4 i0 = ((const int4*)fi)[0];
  int4 i1 = ((const int4*)fi)[1];
  int4 i2 = ((const int4*)fi)[2];
  int idx[10] = {i0.x, i0.y, i0.z, i0.w, i1.x, i1.y, i1.z, i1.w, i2.x, i2.y};
  const uint4* hb = h2 + (size_t)b * N1 * 2;
  float acc[32];
#pragma unroll
  for (int o = 0; o < 32; ++o) acc[o] = 0.f;
#pragma unroll
  for (int k = 0; k < KC; ++k) {
    uint4 A = hb[idx[k]];
    uint4 B = hb[idx[k] + 1];
    float v[16] = {bfLo(A.x), bfHi(A.x), bfLo(A.y), bfHi(A.y),
                   bfLo(A.z), bfHi(A.z), bfLo(A.w), bfHi(A.w),
                   bfLo(B.x), bfHi(B.x), bfLo(B.y), bfHi(B.y),
                   bfLo(B.z), bfHi(B.z), bfLo(B.w), bfHi(B.w)};
    const float* wk = wt + k * 512;
#pragma unroll
    for (int c = 0; c < 16; ++c)
#pragma unroll
      for (int o = 0; o < 32; ++o)
        acc[o] = fmaf(v[c], wk[c * 32 + o], acc[o]);
  }
#pragma unroll
  for (int o = 0; o < 32; ++o) acc[o] += b2[o];
#pragma unroll
  for (int off = 1; off < 4; off <<= 1)
#pragma unroll
    for (int o = 0; o < 32; ++o)
      acc[o] = fmaxf(acc[o], __shfl_xor(acc[o], off));
  float4 r0, r1;
  r0.x = sel4(p, acc[0], acc[8],  acc[16], acc[24]);
  r0.y = sel4(p, acc[1], acc[9],  acc[17], acc[25]);
  r0.z = sel4(p, acc[2], acc[10], acc[18], acc[26]);
  r0.w = sel4(p, acc[3], acc[11], acc[19], acc[27]);
  r1.x = sel4(p, acc[4], acc[12], acc[20], acc[28]);
  r1.y = sel4(p, acc[5], acc[13], acc[21], acc[29]);
  r1.z = sel4(p, acc[6], acc[14], acc[22], acc[30]);
  r1.w = sel4(p, acc[7], acc[15], acc[23], acc[31]);
  float* dst = h3 + ((size_t)b * N2 + j) * 32 + p * 8;
  *(float4*)dst = r0;
  *(float4*)(dst + 4) = r1;
}

// ---- conv3 (32->10) + mean, thread = (b,j); CH = compile-time channel half ----
template<int CH>
__global__ __launch_bounds__(256) void k3(
    const float* __restrict__ h3, const int* __restrict__ conv_t2,
    const float* __restrict__ wt, float* __restrict__ out) {
  int blk = blockIdx.x;
  int b = blk & 7;
  int j = (blk >> 3) * 256 + threadIdx.x;
  int idx[KC];
#pragma unroll
  for (int k = 0; k < KC; ++k) idx[k] = conv_t2[(size_t)j * KC + k] * 32 + CH * 16;
  const float* hb = h3 + (size_t)b * N2 * 32;
  float acc[10];
#pragma unroll
  for (int o = 0; o < 10; ++o) acc[o] = 0.f;
#pragma unroll
  for (int k = 0; k < KC; ++k) {
    const float4* ph = (const float4*)(hb + idx[k]);
#pragma unroll
    for (int q = 0; q < 4; ++q) {
      float4 t = ph[q];
#pragma unroll
      for (int o = 0; o < 10; ++o)
        acc[o] = fmaf(t.x, wt[k * 320 + (CH * 16 + q * 4 + 0) * 10 + o],
                 fmaf(t.y, wt[k * 320 + (CH * 16 + q * 4 + 1) * 10 + o],
                 fmaf(t.z, wt[k * 320 + (CH * 16 + q * 4 + 2) * 10 + o],
                 fmaf(t.w, wt[k * 320 + (CH * 16 + q * 4 + 3) * 10 + o], acc[o]))));
    }
  }
#pragma unroll
  for (int off = 1; off < 64; off <<= 1)
#pragma unroll
    for (int o = 0; o < 10; ++o) acc[o] += __shfl_xor(acc[o], off);
  int lane = threadIdx.x & 63;
  float s = acc[0];
  s = (lane == 1) ? acc[1] : s;
  s = (lane == 2) ? acc[2] : s;
  s = (lane == 3) ? acc[3] : s;
  s = (lane == 4) ? acc[4] : s;
  s = (lane == 5) ? acc[5] : s;
  s = (lane == 6) ? acc[6] : s;
  s = (lane == 7) ? acc[7] : s;
  s = (lane == 8) ? acc[8] : s;
  s = (lane == 9) ? acc[9] : s;
  if (lane < 10) atomicAdd(&out[b * 10 + lane], s * (1.0f / N2));
}

extern "C" void kernel_launch(void* const* d_in, const int* in_sizes, int n_in,
                              void* d_out, int out_size, void* d_ws, size_t ws_size,
                              hipStream_t stream) {
  const float* x       = (const float*)d_in[0];
  const int*   conv_t0 = (const int*)d_in[1];
  const int*   conv_t1 = (const int*)d_in[2];
  const int*   conv_t2 = (const int*)d_in[3];
  const int*   adj0    = (const int*)d_in[4];
  const int*   adj1    = (const int*)d_in[5];
  const int*   pool0   = (const int*)d_in[6];
  const int*   pool1   = (const int*)d_in[7];
  const float* w1      = (const float*)d_in[8];
  const float* b1      = (const float*)d_in[9];
  const float* w2      = (const float*)d_in[10];
  const float* b2      = (const float*)d_in[11];
  const float* w3      = (const float*)d_in[12];
  const float* b3      = (const float*)d_in[13];
  float* out  = (float*)d_out;
  float* wsf  = (float*)d_ws;

  // word layout: xT/h3 alias (both 5,242,880 words), h2 bf16 5,242,880,
  // fidx0 3,932,160, fidx1 983,040, weights 8,800  -> total 61.6 MB
  ushort4* xT  = (ushort4*)wsf;               // bf16 [b][n][4]; dead after k1
  float* h3b   = wsf;                         // aliases xT exactly
  ushort4* h2b = (ushort4*)(wsf + 5242880);   // bf16 [b][j][16]
  int* fidx0   = (int*)(wsf + 2 * 5242880);
  int* fidx1   = fidx0 + (size_t)N1 * 48;
  float* w1t   = (float*)(fidx1 + (size_t)N2 * 48);
  float* w2t   = w1t + 480;
  float* w3t   = w2t + 5120;

  kprep<<<20, 256, 0, stream>>>(w1, w2, w3, b3, w1t, w2t, w3t, out);
  ktransx<<<NB * (N0 / 256), 256, 0, stream>>>(x, xT);
  kfidx<<<N1 * 4 / 256, 256, 0, stream>>>(conv_t0, conv_t1, adj0, adj1, pool0, pool1,
                                          fidx0, fidx1);
  k1<<<NB * (N1 * 4 / 256), 256, 0, stream>>>((const uint2*)xT, fidx0, w1t, b1, h2b);
  k2<<<NB * (N2 * 4 / 256), 256, 0, stream>>>((const uint4*)h2b, fidx1, w2t, b2, h3b);
  k3<0><<<NB * (N2 / 256), 256, 0, stream>>>(h3b, conv_t2, w3t, out);
  k3<1><<<NB * (N2 / 256), 256, 0, stream>>>(h3b, conv_t2, w3t, out);
}

// Round 6
// 260.397 us; speedup vs baseline: 10.2818x; 1.4422x over previous
//
#include <hip/hip_runtime.h>

#define NB 8
#define CIN 3
#define N0 327680
#define N1 81920
#define N2 20480
#define KC 10
#define KA 4

typedef __attribute__((ext_vector_type(8))) short bf16x8;
typedef __attribute__((ext_vector_type(4))) float f32x4;

__device__ __forceinline__ unsigned f2bf(float f) {          // RNE float->bf16
  unsigned u = __float_as_uint(f);
  return (u + 0x7FFFu + ((u >> 16) & 1u)) >> 16;
}
__device__ __forceinline__ float bfLo(unsigned w) { return __uint_as_float(w << 16); }
__device__ __forceinline__ float bfHi(unsigned w) { return __uint_as_float(w & 0xFFFF0000u); }

__device__ __forceinline__ float sel4(int p, float a, float b, float c, float d) {
  float r = (p == 1) ? b : a;
  r = (p == 2) ? c : r;
  r = (p == 3) ? d : r;
  return r;
}

// ---- w1 -> [k][c][o] fp32; w2 -> per-lane bf16 B-fragments; w3 -> [k][c][o]; out = bias3 ----
__global__ __launch_bounds__(256) void kprep(
    const float* __restrict__ w1, const float* __restrict__ w2,
    const float* __restrict__ w3, const float* __restrict__ b3,
    float* __restrict__ w1t, unsigned short* __restrict__ wB,
    float* __restrict__ w3t, float* __restrict__ out) {
  int t = blockIdx.x * 256 + threadIdx.x;
  if (t < 480)  { int o = t & 15, c = (t >> 4) % 3, k = t / 48;
                  w1t[t] = w1[(o * 3 + c) * KC + k]; }
  if (t < 5120) {
    // wB[q][nt][lane][e] : B-frag for mfma_f32_16x16x32_bf16, K-chunk q, N-tile nt
    int e = t & 7, l = (t >> 3) & 63, nt = (t >> 9) & 1, q = t >> 10;
    int kc = q * 32 + ((l >> 4) * 8) + e;          // reduction index = tap*16 + c
    int tap = kc >> 4, c = kc & 15;
    int o = nt * 16 + (l & 15);
    wB[t] = (unsigned short)f2bf(w2[(o * 16 + c) * KC + tap]);
  }
  if (t < 3200) { int o = t % 10, r = t / 10, c = r & 31, k = r >> 5;
                  w3t[t] = w3[(o * 32 + c) * KC + k]; }
  if (t < 80)   out[t] = b3[t % 10];
}

// ---- x [b][c][n] -> xT bf16 [b][n][4] ----
__global__ __launch_bounds__(256) void ktransx(
    const float* __restrict__ x, ushort4* __restrict__ xT) {
  int blk = blockIdx.x;
  int b = blk / (N0 / 256);
  int n = (blk % (N0 / 256)) * 256 + threadIdx.x;
  size_t src = (size_t)b * CIN * N0 + n;
  ushort4 w;
  w.x = (unsigned short)f2bf(x[src]);
  w.y = (unsigned short)f2bf(x[src + N0]);
  w.z = (unsigned short)f2bf(x[src + 2 * (size_t)N0]);
  w.w = 0;
  xT[(size_t)b * N0 + n] = w;
}

// ---- index tables: fidx0 [j][p][12] (uint2 units); fidxP [jp][10] byte offsets ----
__global__ __launch_bounds__(256) void kfidx(
    const int* __restrict__ conv_t0, const int* __restrict__ conv_t1,
    const int* __restrict__ adj0, const int* __restrict__ adj1,
    const int* __restrict__ pool0, const int* __restrict__ pool1,
    int* __restrict__ fidx0, int* __restrict__ fidxP) {
  int t = blockIdx.x * 256 + threadIdx.x;       // N1*4 threads
  int j = t >> 2, p = t & 3;
  int pj = pool0[j];
  int pos = adj0[pj * KA + p];
#pragma unroll
  for (int k = 0; k < KC; ++k)
    fidx0[(size_t)j * 48 + p * 12 + k] = conv_t0[pos * KC + k];        // uint2 index
  if (j < N2) {
    int qj = pool1[j];
    int qos = adj1[qj * KA + p];
#pragma unroll
    for (int k = 0; k < KC; ++k)
      fidxP[((size_t)j * 4 + p) * 10 + k] = conv_t1[qos * KC + k] * 32; // byte offset
  }
}

// ---- conv1 (3->16) + maxpool0, thread = (b,j,p); bf16 in, fp32 math, bf16 out ----
__global__ __launch_bounds__(256) void k1(
    const uint2* __restrict__ xT, const int* __restrict__ fidx0,
    const float* __restrict__ wt, const float* __restrict__ b1,
    ushort4* __restrict__ h2) {
  int blk = blockIdx.x;
  int b = blk & 7;                              // XCD-pinned batch
  int slot = (blk >> 3) * 256 + threadIdx.x;
  int j = slot >> 2, p = slot & 3;
  const int* fi = fidx0 + (size_t)j * 48 + p * 12;
  int4 i0 = ((const int4*)fi)[0];
  int4 i1 = ((const int4*)fi)[1];
  int4 i2 = ((const int4*)fi)[2];
  int idx[10] = {i0.x, i0.y, i0.z, i0.w, i1.x, i1.y, i1.z, i1.w, i2.x, i2.y};
  const uint2* xb = xT + (size_t)b * N0;
  float acc[16];
#pragma unroll
  for (int o = 0; o < 16; ++o) acc[o] = 0.f;
#pragma unroll
  for (int k = 0; k < KC; ++k) {
    uint2 v = xb[idx[k]];
    float v0 = bfLo(v.x), v1 = bfHi(v.x), v2 = bfLo(v.y);
    const float* wk = wt + k * 48;
#pragma unroll
    for (int o = 0; o < 16; ++o)
      acc[o] = fmaf(v0, wk[o], fmaf(v1, wk[16 + o], fmaf(v2, wk[32 + o], acc[o])));
  }
#pragma unroll
  for (int o = 0; o < 16; ++o) acc[o] += b1[o];   // bias before max: commutes
#pragma unroll
  for (int off = 1; off < 4; off <<= 1)
#pragma unroll
    for (int o = 0; o < 16; ++o)
      acc[o] = fmaxf(acc[o], __shfl_xor(acc[o], off));
  ushort4 r;
  r.x = (unsigned short)f2bf(sel4(p, acc[0], acc[4], acc[8],  acc[12]));
  r.y = (unsigned short)f2bf(sel4(p, acc[1], acc[5], acc[9],  acc[13]));
  r.z = (unsigned short)f2bf(sel4(p, acc[2], acc[6], acc[10], acc[14]));
  r.w = (unsigned short)f2bf(sel4(p, acc[3], acc[7], acc[11], acc[15]));
  h2[((size_t)b * N1 + j) * 4 + p] = r;
}

// ---- conv2 (16->32) + maxpool1 via MFMA: gather-GEMM M=655360 K=160 N=32 ----
// Tile = 16 jp-rows (4 j's x 4 p, p minor). A-frag: lane=row l&15, kc=(l>>4)*8..+8
// -> one 16B gather per lane per K-chunk. D-frag: row=(l>>4)*4+reg, col=l&15
// -> the 4 regs are the 4 pool positions of j = tile*4 + (l>>4): maxpool in-register.
__global__ __launch_bounds__(256) void k2(
    const char* __restrict__ h2, const int* __restrict__ fidxP,
    const bf16x8* __restrict__ wB, const float* __restrict__ b2,
    float* __restrict__ h3) {
  int blk = blockIdx.x;
  int b = blk & 7;
  int wave = threadIdx.x >> 6;
  int lane = threadIdx.x & 63;
  int tile0 = ((blk >> 3) * 4 + wave) * 8;      // 8 tiles/wave; 5120 tiles/batch
  const char* hb = h2 + (size_t)b * N1 * 32;

  bf16x8 Bf[10];
#pragma unroll
  for (int i = 0; i < 10; ++i) Bf[i] = wB[i * 64 + lane];
  float bias0 = b2[lane & 15];
  float bias1 = b2[16 + (lane & 15)];
  int half16 = ((lane >> 4) & 1) * 16;          // c-half byte offset
  int oddsel = (lane >> 5) & 1;                 // even/odd tap select

#pragma unroll 2
  for (int i = 0; i < 8; ++i) {
    int tile = tile0 + i;
    const int* fp = fidxP + ((size_t)tile * 16 + (lane & 15)) * 10;
    f32x4 acc0 = {0.f, 0.f, 0.f, 0.f};
    f32x4 acc1 = {0.f, 0.f, 0.f, 0.f};
#pragma unroll
    for (int q = 0; q < 5; ++q) {
      int2 tp = *(const int2*)(fp + 2 * q);
      int off = (oddsel ? tp.y : tp.x) + half16;
      bf16x8 A = *(const bf16x8*)(hb + off);
      acc0 = __builtin_amdgcn_mfma_f32_16x16x32_bf16(A, Bf[q * 2 + 0], acc0, 0, 0, 0);
      acc1 = __builtin_amdgcn_mfma_f32_16x16x32_bf16(A, Bf[q * 2 + 1], acc1, 0, 0, 0);
    }
    float m0 = fmaxf(fmaxf(acc0[0], acc0[1]), fmaxf(acc0[2], acc0[3])) + bias0;
    float m1 = fmaxf(fmaxf(acc1[0], acc1[1]), fmaxf(acc1[2], acc1[3])) + bias1;
    int j = tile * 4 + (lane >> 4);
    float* dst = h3 + ((size_t)b * N2 + j) * 32 + (lane & 15);
    dst[0]  = m0;
    dst[16] = m1;
  }
}

// ---- conv3 (32->10) + mean, thread = (b,j); CH = compile-time channel half ----
template<int CH>
__global__ __launch_bounds__(256) void k3(
    const float* __restrict__ h3, const int* __restrict__ conv_t2,
    const float* __restrict__ wt, float* __restrict__ out) {
  int blk = blockIdx.x;
  int b = blk & 7;
  int j = (blk >> 3) * 256 + threadIdx.x;
  int idx[KC];
#pragma unroll
  for (int k = 0; k < KC; ++k) idx[k] = conv_t2[(size_t)j * KC + k] * 32 + CH * 16;
  const float* hb = h3 + (size_t)b * N2 * 32;
  float acc[10];
#pragma unroll
  for (int o = 0; o < 10; ++o) acc[o] = 0.f;
#pragma unroll
  for (int k = 0; k < KC; ++k) {
    const float4* ph = (const float4*)(hb + idx[k]);
#pragma unroll
    for (int q = 0; q < 4; ++q) {
      float4 t = ph[q];
#pragma unroll
      for (int o = 0; o < 10; ++o)
        acc[o] = fmaf(t.x, wt[k * 320 + (CH * 16 + q * 4 + 0) * 10 + o],
                 fmaf(t.y, wt[k * 320 + (CH * 16 + q * 4 + 1) * 10 + o],
                 fmaf(t.z, wt[k * 320 + (CH * 16 + q * 4 + 2) * 10 + o],
                 fmaf(t.w, wt[k * 320 + (CH * 16 + q * 4 + 3) * 10 + o], acc[o]))));
    }
  }
#pragma unroll
  for (int off = 1; off < 64; off <<= 1)
#pragma unroll
    for (int o = 0; o < 10; ++o) acc[o] += __shfl_xor(acc[o], off);
  int lane = threadIdx.x & 63;
  float s = acc[0];
  s = (lane == 1) ? acc[1] : s;
  s = (lane == 2) ? acc[2] : s;
  s = (lane == 3) ? acc[3] : s;
  s = (lane == 4) ? acc[4] : s;
  s = (lane == 5) ? acc[5] : s;
  s = (lane == 6) ? acc[6] : s;
  s = (lane == 7) ? acc[7] : s;
  s = (lane == 8) ? acc[8] : s;
  s = (lane == 9) ? acc[9] : s;
  if (lane < 10) atomicAdd(&out[b * 10 + lane], s * (1.0f / N2));
}

extern "C" void kernel_launch(void* const* d_in, const int* in_sizes, int n_in,
                              void* d_out, int out_size, void* d_ws, size_t ws_size,
                              hipStream_t stream) {
  const float* x       = (const float*)d_in[0];
  const int*   conv_t0 = (const int*)d_in[1];
  const int*   conv_t1 = (const int*)d_in[2];
  const int*   conv_t2 = (const int*)d_in[3];
  const int*   adj0    = (const int*)d_in[4];
  const int*   adj1    = (const int*)d_in[5];
  const int*   pool0   = (const int*)d_in[6];
  const int*   pool1   = (const int*)d_in[7];
  const float* w1      = (const float*)d_in[8];
  const float* b1      = (const float*)d_in[9];
  const float* w2      = (const float*)d_in[10];
  const float* b2      = (const float*)d_in[11];
  const float* w3      = (const float*)d_in[12];
  const float* b3      = (const float*)d_in[13];
  float* out  = (float*)d_out;
  float* wsf  = (float*)d_ws;

  // word layout: xT/h3 alias 5,242,880 | h2 bf16 5,242,880 | fidx0 3,932,160 |
  // fidxP 819,200 | wB 2,560 | w1t 480 | w3t 3,200   -> ~61 MB
  ushort4* xT  = (ushort4*)wsf;                       // dead after k1
  float* h3b   = wsf;                                 // aliases xT
  ushort4* h2b = (ushort4*)(wsf + 5242880);
  int* fidx0   = (int*)(wsf + 2 * 5242880);
  int* fidxP   = fidx0 + (size_t)N1 * 48;
  unsigned short* wB = (unsigned short*)(fidxP + (size_t)N2 * 4 * 10);
  float* w1t   = (float*)(wB + 5120);
  float* w3t   = w1t + 480;

  kprep<<<20, 256, 0, stream>>>(w1, w2, w3, b3, w1t, wB, w3t, out);
  ktransx<<<NB * (N0 / 256), 256, 0, stream>>>(x, xT);
  kfidx<<<N1 * 4 / 256, 256, 0, stream>>>(conv_t0, conv_t1, adj0, adj1, pool0, pool1,
                                          fidx0, fidxP);
  k1<<<NB * (N1 * 4 / 256), 256, 0, stream>>>((const uint2*)xT, fidx0, w1t, b1, h2b);
  k2<<<1280, 256, 0, stream>>>((const char*)h2b, fidxP, (const bf16x8*)wB, b2, h3b);
  k3<0><<<NB * (N2 / 256), 256, 0, stream>>>(h3b, conv_t2, w3t, out);
  k3<1><<<NB * (N2 / 256), 256, 0, stream>>>(h3b, conv_t2, w3t, out);
}

// Round 7
// 227.819 us; speedup vs baseline: 11.7521x; 1.1430x over previous
//
#include <hip/hip_runtime.h>

#define NB 8
#define CIN 3
#define N0 327680
#define N1 81920
#define N2 20480
#define KC 10
#define KA 4

typedef __attribute__((ext_vector_type(8))) short bf16x8;
typedef __attribute__((ext_vector_type(4))) float f32x4;

__device__ __forceinline__ unsigned f2bf(float f) {          // RNE float->bf16
  unsigned u = __float_as_uint(f);
  return (u + 0x7FFFu + ((u >> 16) & 1u)) >> 16;
}
__device__ __forceinline__ float bfLo(unsigned w) { return __uint_as_float(w << 16); }
__device__ __forceinline__ float bfHi(unsigned w) { return __uint_as_float(w & 0xFFFF0000u); }

__device__ __forceinline__ float sel4(int p, float a, float b, float c, float d) {
  float r = (p == 1) ? b : a;
  r = (p == 2) ? c : r;
  r = (p == 3) ? d : r;
  return r;
}

// ---- w1 -> [k][c][o] fp32; w2 -> per-lane bf16 B-fragments; w3 -> [k][c][o]; out = bias3 ----
__global__ __launch_bounds__(256) void kprep(
    const float* __restrict__ w1, const float* __restrict__ w2,
    const float* __restrict__ w3, const float* __restrict__ b3,
    float* __restrict__ w1t, unsigned short* __restrict__ wB,
    float* __restrict__ w3t, float* __restrict__ out) {
  int t = blockIdx.x * 256 + threadIdx.x;
  if (t < 480)  { int o = t & 15, c = (t >> 4) % 3, k = t / 48;
                  w1t[t] = w1[(o * 3 + c) * KC + k]; }
  if (t < 5120) {
    // wB[q][nt][lane][e] : B-frag for mfma_f32_16x16x32_bf16, K-chunk q, N-tile nt
    int e = t & 7, l = (t >> 3) & 63, nt = (t >> 9) & 1, q = t >> 10;
    int kc = q * 32 + ((l >> 4) * 8) + e;          // reduction index = tap*16 + c
    int tap = kc >> 4, c = kc & 15;
    int o = nt * 16 + (l & 15);
    wB[t] = (unsigned short)f2bf(w2[(o * 16 + c) * KC + tap]);
  }
  if (t < 3200) { int o = t % 10, r = t / 10, c = r & 31, k = r >> 5;
                  w3t[t] = w3[(o * 32 + c) * KC + k]; }
  if (t < 80)   out[t] = b3[t % 10];
}

// ---- x [b][c][n] -> xT2 [bp][n][8 bf16] : {b0c0,b0c1 | b0c2,0 | b1c0,b1c1 | b1c2,0} ----
__global__ __launch_bounds__(256) void ktransx(
    const float* __restrict__ x, uint4* __restrict__ xT2) {
  int blk = blockIdx.x;
  int bp = blk & 3;
  int n = (blk >> 2) * 256 + threadIdx.x;
  size_t s0 = (size_t)(2 * bp) * CIN * N0 + n;
  size_t s1 = s0 + (size_t)CIN * N0;
  uint4 w;
  w.x = f2bf(x[s0]) | (f2bf(x[s0 + N0]) << 16);
  w.y = f2bf(x[s0 + 2 * (size_t)N0]);
  w.z = f2bf(x[s1]) | (f2bf(x[s1 + N0]) << 16);
  w.w = f2bf(x[s1 + 2 * (size_t)N0]);
  xT2[(size_t)bp * N0 + n] = w;
}

// ---- index tables: fidx0 [j][p][12] (row indices); fidxP [jp][10] byte offsets ----
__global__ __launch_bounds__(256) void kfidx(
    const int* __restrict__ conv_t0, const int* __restrict__ conv_t1,
    const int* __restrict__ adj0, const int* __restrict__ adj1,
    const int* __restrict__ pool0, const int* __restrict__ pool1,
    int* __restrict__ fidx0, int* __restrict__ fidxP) {
  int t = blockIdx.x * 256 + threadIdx.x;       // N1*4 threads
  int j = t >> 2, p = t & 3;
  int pj = pool0[j];
  int pos = adj0[pj * KA + p];
#pragma unroll
  for (int k = 0; k < KC; ++k)
    fidx0[(size_t)j * 48 + p * 12 + k] = conv_t0[pos * KC + k];        // uint4 index
  if (j < N2) {
    int qj = pool1[j];
    int qos = adj1[qj * KA + p];
#pragma unroll
    for (int k = 0; k < KC; ++k)
      fidxP[((size_t)j * 4 + p) * 10 + k] = conv_t1[qos * KC + k] * 32; // byte offset
  }
}

// ---- conv1 (3->16) + maxpool0, thread = (j,p,bpair): one 16B gather feeds 2 batches ----
__global__ __launch_bounds__(256) void k1(
    const uint4* __restrict__ xT2, const int* __restrict__ fidx0,
    const float* __restrict__ wt, const float* __restrict__ b1,
    ushort4* __restrict__ h2) {
  int blk = blockIdx.x;
  int bp = blk & 3;                             // XCD-pair-pinned batch pair
  int tid = threadIdx.x;
  int p = tid & 3;
  int j = (blk >> 2) * 64 + (tid >> 2);
  const int* fi = fidx0 + (size_t)j * 48 + p * 12;
  int4 i0 = ((const int4*)fi)[0];
  int4 i1 = ((const int4*)fi)[1];
  int4 i2 = ((const int4*)fi)[2];
  int idx[10] = {i0.x, i0.y, i0.z, i0.w, i1.x, i1.y, i1.z, i1.w, i2.x, i2.y};
  const uint4* xb = xT2 + (size_t)bp * N0;
  float a0[16], a1[16];
#pragma unroll
  for (int o = 0; o < 16; ++o) { a0[o] = 0.f; a1[o] = 0.f; }
#pragma unroll
  for (int k = 0; k < KC; ++k) {
    uint4 v = xb[idx[k]];
    float v0 = bfLo(v.x), v1 = bfHi(v.x), v2 = bfLo(v.y);
    float u0 = bfLo(v.z), u1 = bfHi(v.z), u2 = bfLo(v.w);
    const float* wk = wt + k * 48;
#pragma unroll
    for (int o = 0; o < 16; ++o) {
      float w0 = wk[o], w1 = wk[16 + o], w2 = wk[32 + o];
      a0[o] = fmaf(v0, w0, fmaf(v1, w1, fmaf(v2, w2, a0[o])));
      a1[o] = fmaf(u0, w0, fmaf(u1, w1, fmaf(u2, w2, a1[o])));
    }
  }
#pragma unroll
  for (int o = 0; o < 16; ++o) { float bb = b1[o]; a0[o] += bb; a1[o] += bb; }
#pragma unroll
  for (int off = 1; off < 4; off <<= 1)
#pragma unroll
    for (int o = 0; o < 16; ++o) {
      a0[o] = fmaxf(a0[o], __shfl_xor(a0[o], off));
      a1[o] = fmaxf(a1[o], __shfl_xor(a1[o], off));
    }
  ushort4 r0, r1;
  r0.x = (unsigned short)f2bf(sel4(p, a0[0], a0[4], a0[8],  a0[12]));
  r0.y = (unsigned short)f2bf(sel4(p, a0[1], a0[5], a0[9],  a0[13]));
  r0.z = (unsigned short)f2bf(sel4(p, a0[2], a0[6], a0[10], a0[14]));
  r0.w = (unsigned short)f2bf(sel4(p, a0[3], a0[7], a0[11], a0[15]));
  r1.x = (unsigned short)f2bf(sel4(p, a1[0], a1[4], a1[8],  a1[12]));
  r1.y = (unsigned short)f2bf(sel4(p, a1[1], a1[5], a1[9],  a1[13]));
  r1.z = (unsigned short)f2bf(sel4(p, a1[2], a1[6], a1[10], a1[14]));
  r1.w = (unsigned short)f2bf(sel4(p, a1[3], a1[7], a1[11], a1[15]));
  h2[((size_t)(2 * bp) * N1 + j) * 4 + p] = r0;
  h2[((size_t)(2 * bp + 1) * N1 + j) * 4 + p] = r1;
}

// ---- conv2 (16->32) + maxpool1 via MFMA gather-GEMM (unchanged from R5) ----
__global__ __launch_bounds__(256) void k2(
    const char* __restrict__ h2, const int* __restrict__ fidxP,
    const bf16x8* __restrict__ wB, const float* __restrict__ b2,
    float* __restrict__ h3) {
  int blk = blockIdx.x;
  int b = blk & 7;
  int wave = threadIdx.x >> 6;
  int lane = threadIdx.x & 63;
  int tile0 = ((blk >> 3) * 4 + wave) * 8;
  const char* hb = h2 + (size_t)b * N1 * 32;

  bf16x8 Bf[10];
#pragma unroll
  for (int i = 0; i < 10; ++i) Bf[i] = wB[i * 64 + lane];
  float bias0 = b2[lane & 15];
  float bias1 = b2[16 + (lane & 15)];
  int half16 = ((lane >> 4) & 1) * 16;
  int oddsel = (lane >> 5) & 1;

#pragma unroll 2
  for (int i = 0; i < 8; ++i) {
    int tile = tile0 + i;
    const int* fp = fidxP + ((size_t)tile * 16 + (lane & 15)) * 10;
    f32x4 acc0 = {0.f, 0.f, 0.f, 0.f};
    f32x4 acc1 = {0.f, 0.f, 0.f, 0.f};
#pragma unroll
    for (int q = 0; q < 5; ++q) {
      int2 tp = *(const int2*)(fp + 2 * q);
      int off = (oddsel ? tp.y : tp.x) + half16;
      bf16x8 A = *(const bf16x8*)(hb + off);
      acc0 = __builtin_amdgcn_mfma_f32_16x16x32_bf16(A, Bf[q * 2 + 0], acc0, 0, 0, 0);
      acc1 = __builtin_amdgcn_mfma_f32_16x16x32_bf16(A, Bf[q * 2 + 1], acc1, 0, 0, 0);
    }
    float m0 = fmaxf(fmaxf(acc0[0], acc0[1]), fmaxf(acc0[2], acc0[3])) + bias0;
    float m1 = fmaxf(fmaxf(acc1[0], acc1[1]), fmaxf(acc1[2], acc1[3])) + bias1;
    int j = tile * 4 + (lane >> 4);
    float* dst = h3 + ((size_t)b * N2 + j) * 32 + (lane & 15);
    dst[0]  = m0;
    dst[16] = m1;
  }
}

// ---- conv3 (32->10) + mean; CH compile-time inside, both halves in one grid ----
template<int CH>
__device__ __forceinline__ void k3_body(
    const float* __restrict__ hb, const int* __restrict__ conv_t2,
    const float* __restrict__ wt, float* __restrict__ out, int b, int j,
    int lane) {
  int idx[KC];
#pragma unroll
  for (int k = 0; k < KC; ++k) idx[k] = conv_t2[(size_t)j * KC + k] * 32 + CH * 16;
  float acc[10];
#pragma unroll
  for (int o = 0; o < 10; ++o) acc[o] = 0.f;
#pragma unroll
  for (int k = 0; k < KC; ++k) {
    const float4* ph = (const float4*)(hb + idx[k]);
#pragma unroll
    for (int q = 0; q < 4; ++q) {
      float4 t = ph[q];
#pragma unroll
      for (int o = 0; o < 10; ++o)
        acc[o] = fmaf(t.x, wt[k * 320 + (CH * 16 + q * 4 + 0) * 10 + o],
                 fmaf(t.y, wt[k * 320 + (CH * 16 + q * 4 + 1) * 10 + o],
                 fmaf(t.z, wt[k * 320 + (CH * 16 + q * 4 + 2) * 10 + o],
                 fmaf(t.w, wt[k * 320 + (CH * 16 + q * 4 + 3) * 10 + o], acc[o]))));
    }
  }
#pragma unroll
  for (int off = 1; off < 64; off <<= 1)
#pragma unroll
    for (int o = 0; o < 10; ++o) acc[o] += __shfl_xor(acc[o], off);
  float s = acc[0];
  s = (lane == 1) ? acc[1] : s;
  s = (lane == 2) ? acc[2] : s;
  s = (lane == 3) ? acc[3] : s;
  s = (lane == 4) ? acc[4] : s;
  s = (lane == 5) ? acc[5] : s;
  s = (lane == 6) ? acc[6] : s;
  s = (lane == 7) ? acc[7] : s;
  s = (lane == 8) ? acc[8] : s;
  s = (lane == 9) ? acc[9] : s;
  if (lane < 10) atomicAdd(&out[b * 10 + lane], s * (1.0f / N2));
}

__global__ __launch_bounds__(256) void k3(
    const float* __restrict__ h3, const int* __restrict__ conv_t2,
    const float* __restrict__ wt, float* __restrict__ out) {
  int blk = blockIdx.x;                         // 8b x 2ch x 80jb = 1280 blocks
  int b = blk & 7;
  int ch = (blk >> 3) & 1;
  int j = (blk >> 4) * 256 + threadIdx.x;
  const float* hb = h3 + (size_t)b * N2 * 32;
  int lane = threadIdx.x & 63;
  if (ch == 0) k3_body<0>(hb, conv_t2, wt, out, b, j, lane);
  else         k3_body<1>(hb, conv_t2, wt, out, b, j, lane);
}

extern "C" void kernel_launch(void* const* d_in, const int* in_sizes, int n_in,
                              void* d_out, int out_size, void* d_ws, size_t ws_size,
                              hipStream_t stream) {
  const float* x       = (const float*)d_in[0];
  const int*   conv_t0 = (const int*)d_in[1];
  const int*   conv_t1 = (const int*)d_in[2];
  const int*   conv_t2 = (const int*)d_in[3];
  const int*   adj0    = (const int*)d_in[4];
  const int*   adj1    = (const int*)d_in[5];
  const int*   pool0   = (const int*)d_in[6];
  const int*   pool1   = (const int*)d_in[7];
  const float* w1      = (const float*)d_in[8];
  const float* b1      = (const float*)d_in[9];
  const float* w2      = (const float*)d_in[10];
  const float* b2      = (const float*)d_in[11];
  const float* w3      = (const float*)d_in[12];
  const float* b3      = (const float*)d_in[13];
  float* out  = (float*)d_out;
  float* wsf  = (float*)d_ws;

  // word layout: xT2/h3 alias 5,242,880 | h2 bf16 5,242,880 | fidx0 3,932,160 |
  // fidxP 819,200 | wB 2,560 | w1t 480 | w3t 3,200   -> ~61 MB
  uint4* xT2   = (uint4*)wsf;                         // dead after k1
  float* h3b   = wsf;                                 // aliases xT2
  ushort4* h2b = (ushort4*)(wsf + 5242880);
  int* fidx0   = (int*)(wsf + 2 * 5242880);
  int* fidxP   = fidx0 + (size_t)N1 * 48;
  unsigned short* wB = (unsigned short*)(fidxP + (size_t)N2 * 4 * 10);
  float* w1t   = (float*)(wB + 5120);
  float* w3t   = w1t + 480;

  kprep<<<20, 256, 0, stream>>>(w1, w2, w3, b3, w1t, wB, w3t, out);
  ktransx<<<4 * (N0 / 256), 256, 0, stream>>>(x, xT2);
  kfidx<<<N1 * 4 / 256, 256, 0, stream>>>(conv_t0, conv_t1, adj0, adj1, pool0, pool1,
                                          fidx0, fidxP);
  k1<<<4 * (N1 / 64), 256, 0, stream>>>(xT2, fidx0, w1t, b1, h2b);
  k2<<<1280, 256, 0, stream>>>((const char*)h2b, fidxP, (const bf16x8*)wB, b2, h3b);
  k3<<<1280, 256, 0, stream>>>(h3b, conv_t2, w3t, out);
}

// Round 8
// 199.802 us; speedup vs baseline: 13.4000x; 1.1402x over previous
//
#include <hip/hip_runtime.h>

#define NB 8
#define CIN 3
#define N0 327680
#define N1 81920
#define N2 20480
#define KC 10
#define KA 4

typedef __attribute__((ext_vector_type(8))) short bf16x8;
typedef __attribute__((ext_vector_type(4))) float f32x4;
typedef uint4 __attribute__((aligned(4))) uint4_u;

__device__ __forceinline__ unsigned f2bf(float f) {          // RNE float->bf16
  unsigned u = __float_as_uint(f);
  return (u + 0x7FFFu + ((u >> 16) & 1u)) >> 16;
}

union bfrag { bf16x8 v; unsigned u[4]; };

// ---- weight prep: wB1 (k1 A/B frags), wB (k2 frags), w3t; out = bias3 ----
__global__ __launch_bounds__(256) void kprep(
    const float* __restrict__ w1, const float* __restrict__ w2,
    const float* __restrict__ w3, const float* __restrict__ b3,
    unsigned short* __restrict__ wB1, unsigned short* __restrict__ wB,
    float* __restrict__ w3t, float* __restrict__ out) {
  int t = blockIdx.x * 256 + threadIdx.x;
  if (t < 1024) {
    // wB1[chunk][lane][e]: B-frag for k1's K=40 gather-GEMM (k = tap*4 + c)
    int ch = t >> 9, rest = t & 511, l = rest >> 3, e = rest & 7;
    int k = ch * 32 + ((l >> 4) * 8) + e;
    int tap = k >> 2, cc = k & 3;
    float v = (tap < KC && cc < CIN) ? w1[((l & 15) * CIN + cc) * KC + tap] : 0.f;
    wB1[t] = (unsigned short)f2bf(v);
  }
  if (t < 5120) {
    // wB[q][nt][lane][e] : B-frag for k2 (reduction index = tap*16 + c)
    int e = t & 7, l = (t >> 3) & 63, nt = (t >> 9) & 1, q = t >> 10;
    int kc = q * 32 + ((l >> 4) * 8) + e;
    int tap = kc >> 4, c = kc & 15;
    int o = nt * 16 + (l & 15);
    wB[t] = (unsigned short)f2bf(w2[(o * 16 + c) * KC + tap]);
  }
  if (t < 3200) { int o = t % 10, r = t / 10, c = r & 31, k = r >> 5;
                  w3t[t] = w3[(o * 32 + c) * KC + k]; }
  if (t < 80)   out[t] = b3[t % 10];
}

// ---- x -> xT12 [bp][n][12B]: {b0c0|b0c1, b0c2|b1c0, b1c1|b1c2} bf16 ----
__global__ __launch_bounds__(256) void ktransx(
    const float* __restrict__ x, uint4* __restrict__ xT12) {
  int blk = blockIdx.x;
  int bp = blk & 3;
  int t = (blk >> 2) * 256 + threadIdx.x;       // handles n = 4t .. 4t+3
  int n = t * 4;
  const float* p0 = x + (size_t)(2 * bp) * CIN * N0 + n;
  const float* p1 = p0 + (size_t)CIN * N0;
  float4 a0 = *(const float4*)(p0);
  float4 a1 = *(const float4*)(p0 + N0);
  float4 a2 = *(const float4*)(p0 + 2 * N0);
  float4 c0 = *(const float4*)(p1);
  float4 c1 = *(const float4*)(p1 + N0);
  float4 c2 = *(const float4*)(p1 + 2 * N0);
  unsigned w[12];
  const float* A0 = &a0.x; const float* A1 = &a1.x; const float* A2 = &a2.x;
  const float* C0 = &c0.x; const float* C1 = &c1.x; const float* C2 = &c2.x;
#pragma unroll
  for (int r = 0; r < 4; ++r) {
    w[r * 3 + 0] = f2bf(A0[r]) | (f2bf(A1[r]) << 16);
    w[r * 3 + 1] = f2bf(A2[r]) | (f2bf(C0[r]) << 16);
    w[r * 3 + 2] = f2bf(C1[r]) | (f2bf(C2[r]) << 16);
  }
  uint4* dst = xT12 + ((size_t)bp * N0 / 4 + t) * 3;
  dst[0] = make_uint4(w[0], w[1], w[2], w[3]);
  dst[1] = make_uint4(w[4], w[5], w[6], w[7]);
  dst[2] = make_uint4(w[8], w[9], w[10], w[11]);
}

// ---- index tables: fidxM [jp][10] byte offsets (x12); fidxP [jp][10] (x32) ----
__global__ __launch_bounds__(256) void kfidx(
    const int* __restrict__ conv_t0, const int* __restrict__ conv_t1,
    const int* __restrict__ adj0, const int* __restrict__ adj1,
    const int* __restrict__ pool0, const int* __restrict__ pool1,
    int* __restrict__ fidxM, int* __restrict__ fidxP) {
  int t = blockIdx.x * 256 + threadIdx.x;       // N1*4 threads
  int j = t >> 2, p = t & 3;
  int pj = pool0[j];
  int pos = adj0[pj * KA + p];
#pragma unroll
  for (int k = 0; k < KC; ++k)
    fidxM[(size_t)t * 10 + k] = conv_t0[pos * KC + k] * 12;   // byte offset, 12B rows
  if (j < N2) {
    int qj = pool1[j];
    int qos = adj1[qj * KA + p];
#pragma unroll
    for (int k = 0; k < KC; ++k)
      fidxP[((size_t)j * 4 + p) * 10 + k] = conv_t1[qos * KC + k] * 32;
  }
}

// ---- conv1 (3->16) + maxpool0 via MFMA gather-GEMM, K=40 (tap*4+c), 2 batches/gather ----
// Tile = 16 jp rows. A row = lane&15; k = (lane>>4)*8+e -> taps {2hi, 2hi+1}: one int2
// idx + two 16B gathers per chunk. D: row = hi*4+reg -> regs = 4 pool cands of j=tile*4+hi.
__global__ __launch_bounds__(256) void k1(
    const char* __restrict__ xT12, const int* __restrict__ fidxM,
    const bf16x8* __restrict__ wB1, const float* __restrict__ b1,
    unsigned short* __restrict__ h2) {
  int blk = blockIdx.x;
  int bp = blk & 3;                             // batch pair, XCD-pinned
  int wave = threadIdx.x >> 6;
  int lane = threadIdx.x & 63;
  int col = lane & 15, hi = lane >> 4;
  int tile0 = ((blk >> 2) * 4 + wave) * 4;      // 4 tiles/wave; 20480 tiles/bpair
  const char* xb = xT12 + (size_t)bp * N0 * 12;
  unsigned short* h2b0 = h2 + (size_t)(2 * bp) * N1 * 16;
  unsigned short* h2b1 = h2 + (size_t)(2 * bp + 1) * N1 * 16;
  bf16x8 B0 = wB1[lane];
  bf16x8 B1 = wB1[64 + lane];
  float bias = b1[col];

#pragma unroll 2
  for (int i = 0; i < 4; ++i) {
    int tile = tile0 + i;
    int r = tile * 16 + col;
    int2 t0 = *(const int2*)(fidxM + (size_t)r * 10 + 2 * hi);
    int2 t1 = *(const int2*)(fidxM + (size_t)r * 10 + 8);
    int a2 = hi ? 0 : t1.x;                     // hi>0: dummy (B1 rows are 0)
    int a3 = hi ? 0 : t1.y;
    uint4 g0 = *(const uint4_u*)(xb + t0.x);
    uint4 g1 = *(const uint4_u*)(xb + t0.y);
    uint4 g2 = *(const uint4_u*)(xb + a2);
    uint4 g3 = *(const uint4_u*)(xb + a3);
    bfrag A0c0, A1c0, A0c1, A1c1;
    A0c0.u[0] = g0.x; A0c0.u[1] = g0.y & 0xFFFFu;
    A0c0.u[2] = g1.x; A0c0.u[3] = g1.y & 0xFFFFu;
    A1c0.u[0] = (g0.y >> 16) | (g0.z << 16); A1c0.u[1] = g0.z >> 16;
    A1c0.u[2] = (g1.y >> 16) | (g1.z << 16); A1c0.u[3] = g1.z >> 16;
    A0c1.u[0] = g2.x; A0c1.u[1] = g2.y & 0xFFFFu;
    A0c1.u[2] = g3.x; A0c1.u[3] = g3.y & 0xFFFFu;
    A1c1.u[0] = (g2.y >> 16) | (g2.z << 16); A1c1.u[1] = g2.z >> 16;
    A1c1.u[2] = (g3.y >> 16) | (g3.z << 16); A1c1.u[3] = g3.z >> 16;
    f32x4 z = {0.f, 0.f, 0.f, 0.f};
    f32x4 acc0 = __builtin_amdgcn_mfma_f32_16x16x32_bf16(A0c0.v, B0, z, 0, 0, 0);
    acc0 = __builtin_amdgcn_mfma_f32_16x16x32_bf16(A0c1.v, B1, acc0, 0, 0, 0);
    f32x4 acc1 = __builtin_amdgcn_mfma_f32_16x16x32_bf16(A1c0.v, B0, z, 0, 0, 0);
    acc1 = __builtin_amdgcn_mfma_f32_16x16x32_bf16(A1c1.v, B1, acc1, 0, 0, 0);
    float m0 = fmaxf(fmaxf(acc0[0], acc0[1]), fmaxf(acc0[2], acc0[3])) + bias;
    float m1 = fmaxf(fmaxf(acc1[0], acc1[1]), fmaxf(acc1[2], acc1[3])) + bias;
    size_t j = (size_t)tile * 4 + hi;
    h2b0[j * 16 + col] = (unsigned short)f2bf(m0);
    h2b1[j * 16 + col] = (unsigned short)f2bf(m1);
  }
}

// ---- conv2 (16->32) + maxpool1 via MFMA gather-GEMM (validated R5 structure) ----
__global__ __launch_bounds__(256) void k2(
    const char* __restrict__ h2, const int* __restrict__ fidxP,
    const bf16x8* __restrict__ wB, const float* __restrict__ b2,
    float* __restrict__ h3) {
  int blk = blockIdx.x;
  int b = blk & 7;
  int wave = threadIdx.x >> 6;
  int lane = threadIdx.x & 63;
  int tile0 = ((blk >> 3) * 4 + wave) * 8;
  const char* hb = h2 + (size_t)b * N1 * 32;

  bf16x8 Bf[10];
#pragma unroll
  for (int i = 0; i < 10; ++i) Bf[i] = wB[i * 64 + lane];
  float bias0 = b2[lane & 15];
  float bias1 = b2[16 + (lane & 15)];
  int half16 = ((lane >> 4) & 1) * 16;
  int oddsel = (lane >> 5) & 1;

#pragma unroll 2
  for (int i = 0; i < 8; ++i) {
    int tile = tile0 + i;
    const int* fp = fidxP + ((size_t)tile * 16 + (lane & 15)) * 10;
    f32x4 acc0 = {0.f, 0.f, 0.f, 0.f};
    f32x4 acc1 = {0.f, 0.f, 0.f, 0.f};
#pragma unroll
    for (int q = 0; q < 5; ++q) {
      int2 tp = *(const int2*)(fp + 2 * q);
      int off = (oddsel ? tp.y : tp.x) + half16;
      bf16x8 A = *(const bf16x8*)(hb + off);
      acc0 = __builtin_amdgcn_mfma_f32_16x16x32_bf16(A, Bf[q * 2 + 0], acc0, 0, 0, 0);
      acc1 = __builtin_amdgcn_mfma_f32_16x16x32_bf16(A, Bf[q * 2 + 1], acc1, 0, 0, 0);
    }
    float m0 = fmaxf(fmaxf(acc0[0], acc0[1]), fmaxf(acc0[2], acc0[3])) + bias0;
    float m1 = fmaxf(fmaxf(acc1[0], acc1[1]), fmaxf(acc1[2], acc1[3])) + bias1;
    int j = tile * 4 + (lane >> 4);
    float* dst = h3 + ((size_t)b * N2 + j) * 32 + (lane & 15);
    dst[0]  = m0;
    dst[16] = m1;
  }
}

// ---- conv3 (32->10) + mean; CH compile-time inside, both halves in one grid ----
template<int CH>
__device__ __forceinline__ void k3_body(
    const float* __restrict__ hb, const int* __restrict__ conv_t2,
    const float* __restrict__ wt, float* __restrict__ out, int b, int j,
    int lane) {
  int idx[KC];
#pragma unroll
  for (int k = 0; k < KC; ++k) idx[k] = conv_t2[(size_t)j * KC + k] * 32 + CH * 16;
  float acc[10];
#pragma unroll
  for (int o = 0; o < 10; ++o) acc[o] = 0.f;
#pragma unroll
  for (int k = 0; k < KC; ++k) {
    const float4* ph = (const float4*)(hb + idx[k]);
#pragma unroll
    for (int q = 0; q < 4; ++q) {
      float4 t = ph[q];
#pragma unroll
      for (int o = 0; o < 10; ++o)
        acc[o] = fmaf(t.x, wt[k * 320 + (CH * 16 + q * 4 + 0) * 10 + o],
                 fmaf(t.y, wt[k * 320 + (CH * 16 + q * 4 + 1) * 10 + o],
                 fmaf(t.z, wt[k * 320 + (CH * 16 + q * 4 + 2) * 10 + o],
                 fmaf(t.w, wt[k * 320 + (CH * 16 + q * 4 + 3) * 10 + o], acc[o]))));
    }
  }
#pragma unroll
  for (int off = 1; off < 64; off <<= 1)
#pragma unroll
    for (int o = 0; o < 10; ++o) acc[o] += __shfl_xor(acc[o], off);
  float s = acc[0];
  s = (lane == 1) ? acc[1] : s;
  s = (lane == 2) ? acc[2] : s;
  s = (lane == 3) ? acc[3] : s;
  s = (lane == 4) ? acc[4] : s;
  s = (lane == 5) ? acc[5] : s;
  s = (lane == 6) ? acc[6] : s;
  s = (lane == 7) ? acc[7] : s;
  s = (lane == 8) ? acc[8] : s;
  s = (lane == 9) ? acc[9] : s;
  if (lane < 10) atomicAdd(&out[b * 10 + lane], s * (1.0f / N2));
}

__global__ __launch_bounds__(256) void k3(
    const float* __restrict__ h3, const int* __restrict__ conv_t2,
    const float* __restrict__ wt, float* __restrict__ out) {
  int blk = blockIdx.x;                         // 8b x 2ch x 80jb = 1280 blocks
  int b = blk & 7;
  int ch = (blk >> 3) & 1;
  int j = (blk >> 4) * 256 + threadIdx.x;
  const float* hb = h3 + (size_t)b * N2 * 32;
  int lane = threadIdx.x & 63;
  if (ch == 0) k3_body<0>(hb, conv_t2, wt, out, b, j, lane);
  else         k3_body<1>(hb, conv_t2, wt, out, b, j, lane);
}

extern "C" void kernel_launch(void* const* d_in, const int* in_sizes, int n_in,
                              void* d_out, int out_size, void* d_ws, size_t ws_size,
                              hipStream_t stream) {
  const float* x       = (const float*)d_in[0];
  const int*   conv_t0 = (const int*)d_in[1];
  const int*   conv_t1 = (const int*)d_in[2];
  const int*   conv_t2 = (const int*)d_in[3];
  const int*   adj0    = (const int*)d_in[4];
  const int*   adj1    = (const int*)d_in[5];
  const int*   pool0   = (const int*)d_in[6];
  const int*   pool1   = (const int*)d_in[7];
  const float* w1      = (const float*)d_in[8];
  const float* b1      = (const float*)d_in[9];
  const float* w2      = (const float*)d_in[10];
  const float* b2      = (const float*)d_in[11];
  const float* w3      = (const float*)d_in[12];
  const float* b3      = (const float*)d_in[13];
  float* out  = (float*)d_out;
  float* wsf  = (float*)d_ws;

  // word layout: h3/xT12 alias 5,242,880 | h2 5,242,880 | fidxM 3,276,800 |
  // fidxP 819,200 | wB1 256 | wB 1,280 | w3t 3,200   -> ~58 MB
  float* h3b   = wsf;                                 // 20,971,520 B
  uint4* xT12  = (uint4*)wsf;                         // 15,728,640 B, aliases h3
  unsigned short* h2b = (unsigned short*)(wsf + 5242880);
  int* fidxM   = (int*)(wsf + 2 * 5242880);
  int* fidxP   = fidxM + (size_t)N1 * 4 * 10;
  unsigned short* wB1 = (unsigned short*)(fidxP + (size_t)N2 * 4 * 10);
  unsigned short* wB  = wB1 + 1024;
  float* w3t   = (float*)(wB + 5120);

  kprep<<<20, 256, 0, stream>>>(w1, w2, w3, b3, wB1, wB, w3t, out);
  ktransx<<<4 * (N0 / 4 / 256), 256, 0, stream>>>(x, xT12);
  kfidx<<<N1 * 4 / 256, 256, 0, stream>>>(conv_t0, conv_t1, adj0, adj1, pool0, pool1,
                                          fidxM, fidxP);
  k1<<<5120, 256, 0, stream>>>((const char*)xT12, fidxM, (const bf16x8*)wB1, b1, h2b);
  k2<<<1280, 256, 0, stream>>>((const char*)h2b, fidxP, (const bf16x8*)wB, b2, h3b);
  k3<<<1280, 256, 0, stream>>>(h3b, conv_t2, w3t, out);
}

// Round 10
// 165.512 us; speedup vs baseline: 16.1761x; 1.2072x over previous
//
#include <hip/hip_runtime.h>

#define NB 8
#define CIN 3
#define N0 327680
#define N1 81920
#define N2 20480
#define KC 10
#define KA 4

typedef __attribute__((ext_vector_type(8))) short bf16x8;
typedef __attribute__((ext_vector_type(4))) float f32x4;
typedef uint4 __attribute__((aligned(4))) uint4_u;
typedef int4  __attribute__((aligned(4))) int4_u;

__device__ __forceinline__ unsigned f2bf(float f) {          // RNE float->bf16
  unsigned u = __float_as_uint(f);
  return (u + 0x7FFFu + ((u >> 16) & 1u)) >> 16;
}

union bfrag { bf16x8 v; unsigned u[4]; };

// ---- weight prep: wB1 (k1 frags), wB (k2 frags), w3t; zero G; out = bias3 ----
__global__ __launch_bounds__(256) void kprep(
    const float* __restrict__ w1, const float* __restrict__ w2,
    const float* __restrict__ w3, const float* __restrict__ b3,
    unsigned short* __restrict__ wB1, unsigned short* __restrict__ wB,
    float* __restrict__ w3t, float* __restrict__ G, float* __restrict__ out) {
  int t = blockIdx.x * 256 + threadIdx.x;
  if (t < 1024) {
    int ch = t >> 9, rest = t & 511, l = rest >> 3, e = rest & 7;
    int k = ch * 32 + ((l >> 4) * 8) + e;
    int tap = k >> 2, cc = k & 3;
    float v = (tap < KC && cc < CIN) ? w1[((l & 15) * CIN + cc) * KC + tap] : 0.f;
    wB1[t] = (unsigned short)f2bf(v);
  }
  if (t < 5120) {
    int e = t & 7, l = (t >> 3) & 63, nt = (t >> 9) & 1, q = t >> 10;
    int kc = q * 32 + ((l >> 4) * 8) + e;
    int tap = kc >> 4, c = kc & 15;
    int o = nt * 16 + (l & 15);
    wB[t] = (unsigned short)f2bf(w2[(o * 16 + c) * KC + tap]);
  }
  if (t < 3200) { int o = t % 10, r = t / 10, c = r & 31, k = r >> 5;
                  w3t[t] = w3[(o * 32 + c) * KC + k]; }
  if (t < 2560) G[t] = 0.f;
  if (t < 80)   out[t] = b3[t % 10];
}

// ---- x -> xT12 [bp][n][12B]: {b0c0|b0c1, b0c2|b1c0, b1c1|b1c2} bf16 ----
__global__ __launch_bounds__(256) void ktransx(
    const float* __restrict__ x, uint4* __restrict__ xT12) {
  int blk = blockIdx.x;
  int bp = blk & 3;
  int t = (blk >> 2) * 256 + threadIdx.x;       // handles n = 4t .. 4t+3
  int n = t * 4;
  const float* p0 = x + (size_t)(2 * bp) * CIN * N0 + n;
  const float* p1 = p0 + (size_t)CIN * N0;
  float4 a0 = *(const float4*)(p0);
  float4 a1 = *(const float4*)(p0 + N0);
  float4 a2 = *(const float4*)(p0 + 2 * N0);
  float4 c0 = *(const float4*)(p1);
  float4 c1 = *(const float4*)(p1 + N0);
  float4 c2 = *(const float4*)(p1 + 2 * N0);
  unsigned w[12];
  const float* A0 = &a0.x; const float* A1 = &a1.x; const float* A2 = &a2.x;
  const float* C0 = &c0.x; const float* C1 = &c1.x; const float* C2 = &c2.x;
#pragma unroll
  for (int r = 0; r < 4; ++r) {
    w[r * 3 + 0] = f2bf(A0[r]) | (f2bf(A1[r]) << 16);
    w[r * 3 + 1] = f2bf(A2[r]) | (f2bf(C0[r]) << 16);
    w[r * 3 + 2] = f2bf(C1[r]) | (f2bf(C2[r]) << 16);
  }
  uint4* dst = xT12 + ((size_t)bp * N0 / 4 + t) * 3;
  dst[0] = make_uint4(w[0], w[1], w[2], w[3]);
  dst[1] = make_uint4(w[4], w[5], w[6], w[7]);
  dst[2] = make_uint4(w[8], w[9], w[10], w[11]);
}

// ---- index tables; also zero A12 ----
// fidxM row (48B): [t0 t1 t8 t9 | t2 t3 t4 t5 | t6 t7 0 0]  (byte offs, x12)
// fidxP row (48B): [e0 e2 e4 e6 | e8 0 o1 o3 | o5 o7 o9 0]  (byte offs, x32)
__global__ __launch_bounds__(256) void kfidx(
    const int* __restrict__ conv_t0, const int* __restrict__ conv_t1,
    const int* __restrict__ adj0, const int* __restrict__ adj1,
    const int* __restrict__ pool0, const int* __restrict__ pool1,
    int* __restrict__ fidxM, int* __restrict__ fidxP, float* __restrict__ A12) {
  int t = blockIdx.x * 256 + threadIdx.x;       // N1*4 threads
  if (t < N2 * 12) A12[t] = 0.f;                // zero histogram table
  int j = t >> 2, p = t & 3;
  int pj = pool0[j];
  int pos = adj0[pj * KA + p];
  const int2* s0 = (const int2*)(conv_t0 + (size_t)pos * 10);
  int2 q0 = s0[0], q1 = s0[1], q2 = s0[2], q3 = s0[3], q4 = s0[4];
  int4_u* dM = (int4_u*)(fidxM + (size_t)t * 12);
  dM[0] = make_int4(q0.x * 12, q0.y * 12, q4.x * 12, q4.y * 12);
  dM[1] = make_int4(q1.x * 12, q1.y * 12, q2.x * 12, q2.y * 12);
  dM[2] = make_int4(q3.x * 12, q3.y * 12, 0, 0);
  if (j < N2) {
    int qj = pool1[j];
    int qos = adj1[qj * KA + p];
    const int2* s1 = (const int2*)(conv_t1 + (size_t)qos * 10);
    int2 r0 = s1[0], r1 = s1[1], r2 = s1[2], r3 = s1[3], r4 = s1[4];
    int4_u* dP = (int4_u*)(fidxP + (size_t)t * 12);
    dP[0] = make_int4(r0.x * 32, r1.x * 32, r2.x * 32, r3.x * 32);
    dP[1] = make_int4(r4.x * 32, 0,          r0.y * 32, r1.y * 32);
    dP[2] = make_int4(r2.y * 32, r3.y * 32, r4.y * 32, 0);
  }
}

// ---- histogram A[n][k] = #{j: conv_t2[j,k] = n} ----
__global__ __launch_bounds__(256) void khist(
    const int* __restrict__ conv_t2, float* __restrict__ A12) {
  int t = blockIdx.x * 256 + threadIdx.x;       // N2*10 threads
  int n = conv_t2[t];
  int k = t % 10;
  atomicAdd(&A12[n * 12 + k], 1.0f);
}

// ---- conv1 (3->16) + maxpool0 via MFMA gather-GEMM; 1 idx + 4 gathers per tile ----
__global__ __launch_bounds__(256, 4) void k1(
    const char* __restrict__ xT12, const int* __restrict__ fidxM,
    const bf16x8* __restrict__ wB1, const float* __restrict__ b1,
    unsigned short* __restrict__ h2) {
  int blk = blockIdx.x;
  int bp = blk & 3;                             // batch pair, XCD-pinned
  int wave = threadIdx.x >> 6;
  int lane = threadIdx.x & 63;
  int col = lane & 15, hi = lane >> 4;
  int tile0 = ((blk >> 2) * 4 + wave) * 4;      // 4 tiles/wave
  const char* xb = xT12 + (size_t)bp * N0 * 12;
  unsigned short* h2b0 = h2 + (size_t)(2 * bp) * N1 * 16;
  unsigned short* h2b1 = h2b0 + (size_t)N1 * 16;
  bf16x8 B0 = wB1[lane];
  bf16x8 B1 = wB1[64 + lane];
  float bias = b1[col];
  int seloff = ((hi + 1) >> 1) << 2;            // ints: hi->{0,4,4,8}

  int4 I[4];
#pragma unroll
  for (int i = 0; i < 4; ++i)
    I[i] = *(const int4_u*)(fidxM + ((size_t)(tile0 + i) * 16 + col) * 12 + seloff);

  uint4 g[4][4];
#pragma unroll
  for (int i = 0; i < 4; ++i) {
    int a0 = (hi == 2) ? I[i].z : I[i].x;       // taps {2hi, 2hi+1}
    int a1 = (hi == 2) ? I[i].w : I[i].y;
    int a2 = (hi == 0) ? I[i].z : 0;            // taps {8,9} (hi=0 only)
    int a3 = (hi == 0) ? I[i].w : 0;
    g[i][0] = *(const uint4_u*)(xb + a0);
    g[i][1] = *(const uint4_u*)(xb + a1);
    g[i][2] = *(const uint4_u*)(xb + a2);
    g[i][3] = *(const uint4_u*)(xb + a3);
  }

#pragma unroll
  for (int i = 0; i < 4; ++i) {
    uint4 g0 = g[i][0], g1 = g[i][1], g2 = g[i][2], g3 = g[i][3];
    bfrag A0c0, A1c0, A0c1, A1c1;
    A0c0.u[0] = g0.x; A0c0.u[1] = g0.y & 0xFFFFu;
    A0c0.u[2] = g1.x; A0c0.u[3] = g1.y & 0xFFFFu;
    A1c0.u[0] = (g0.y >> 16) | (g0.z << 16); A1c0.u[1] = g0.z >> 16;
    A1c0.u[2] = (g1.y >> 16) | (g1.z << 16); A1c0.u[3] = g1.z >> 16;
    A0c1.u[0] = g2.x; A0c1.u[1] = g2.y & 0xFFFFu;
    A0c1.u[2] = g3.x; A0c1.u[3] = g3.y & 0xFFFFu;
    A1c1.u[0] = (g2.y >> 16) | (g2.z << 16); A1c1.u[1] = g2.z >> 16;
    A1c1.u[2] = (g3.y >> 16) | (g3.z << 16); A1c1.u[3] = g3.z >> 16;
    f32x4 z = {0.f, 0.f, 0.f, 0.f};
    f32x4 acc0 = __builtin_amdgcn_mfma_f32_16x16x32_bf16(A0c0.v, B0, z, 0, 0, 0);
    acc0 = __builtin_amdgcn_mfma_f32_16x16x32_bf16(A0c1.v, B1, acc0, 0, 0, 0);
    f32x4 acc1 = __builtin_amdgcn_mfma_f32_16x16x32_bf16(A1c0.v, B0, z, 0, 0, 0);
    acc1 = __builtin_amdgcn_mfma_f32_16x16x32_bf16(A1c1.v, B1, acc1, 0, 0, 0);
    float m0 = fmaxf(fmaxf(acc0[0], acc0[1]), fmaxf(acc0[2], acc0[3])) + bias;
    float m1 = fmaxf(fmaxf(acc1[0], acc1[1]), fmaxf(acc1[2], acc1[3])) + bias;
    size_t j = (size_t)(tile0 + i) * 4 + hi;
    h2b0[j * 16 + col] = (unsigned short)f2bf(m0);
    h2b1[j * 16 + col] = (unsigned short)f2bf(m1);
  }
}

// ---- conv2 (16->32) + maxpool1 via MFMA gather-GEMM; 2 idx + 5 gathers per tile ----
__global__ __launch_bounds__(256) void k2(
    const char* __restrict__ h2, const int* __restrict__ fidxP,
    const bf16x8* __restrict__ wB, const float* __restrict__ b2,
    float* __restrict__ h3) {
  int blk = blockIdx.x;
  int b = blk & 7;
  int wave = threadIdx.x >> 6;
  int lane = threadIdx.x & 63;
  int col = lane & 15;
  int odd = (lane >> 5) & 1;
  int tile0 = ((blk >> 3) * 4 + wave) * 8;
  const char* hb = h2 + (size_t)b * N1 * 32 + ((lane >> 4) & 1) * 16;

  bf16x8 Bf[10];
#pragma unroll
  for (int i = 0; i < 10; ++i) Bf[i] = wB[i * 64 + lane];
  float bias0 = b2[col];
  float bias1 = b2[16 + col];

#pragma unroll 2
  for (int i = 0; i < 8; ++i) {
    int tile = tile0 + i;
    const int* fp = fidxP + ((size_t)tile * 16 + col) * 12 + odd * 6;
    int4 T = *(const int4_u*)fp;                // 4 taps of my parity
    int  T4 = fp[4];                            // 5th tap
    f32x4 acc0 = {0.f, 0.f, 0.f, 0.f};
    f32x4 acc1 = {0.f, 0.f, 0.f, 0.f};
    bf16x8 A;
    A = *(const bf16x8*)(hb + T.x);
    acc0 = __builtin_amdgcn_mfma_f32_16x16x32_bf16(A, Bf[0], acc0, 0, 0, 0);
    acc1 = __builtin_amdgcn_mfma_f32_16x16x32_bf16(A, Bf[1], acc1, 0, 0, 0);
    A = *(const bf16x8*)(hb + T.y);
    acc0 = __builtin_amdgcn_mfma_f32_16x16x32_bf16(A, Bf[2], acc0, 0, 0, 0);
    acc1 = __builtin_amdgcn_mfma_f32_16x16x32_bf16(A, Bf[3], acc1, 0, 0, 0);
    A = *(const bf16x8*)(hb + T.z);
    acc0 = __builtin_amdgcn_mfma_f32_16x16x32_bf16(A, Bf[4], acc0, 0, 0, 0);
    acc1 = __builtin_amdgcn_mfma_f32_16x16x32_bf16(A, Bf[5], acc1, 0, 0, 0);
    A = *(const bf16x8*)(hb + T.w);
    acc0 = __builtin_amdgcn_mfma_f32_16x16x32_bf16(A, Bf[6], acc0, 0, 0, 0);
    acc1 = __builtin_amdgcn_mfma_f32_16x16x32_bf16(A, Bf[7], acc1, 0, 0, 0);
    A = *(const bf16x8*)(hb + T4);
    acc0 = __builtin_amdgcn_mfma_f32_16x16x32_bf16(A, Bf[8], acc0, 0, 0, 0);
    acc1 = __builtin_amdgcn_mfma_f32_16x16x32_bf16(A, Bf[9], acc1, 0, 0, 0);
    float m0 = fmaxf(fmaxf(acc0[0], acc0[1]), fmaxf(acc0[2], acc0[3])) + bias0;
    float m1 = fmaxf(fmaxf(acc1[0], acc1[1]), fmaxf(acc1[2], acc1[3])) + bias1;
    int j = tile * 4 + (lane >> 4);
    float* dst = h3 + ((size_t)b * N2 + j) * 32 + col;
    dst[0]  = m0;
    dst[16] = m1;
  }
}

// ---- G[b][c][k] = sum_n A[n][k] * h3[b][n][c] : sequential h3 stream ----
#define K3B_NCH 256
__global__ __launch_bounds__(256) void k3b(
    const float* __restrict__ h3, const float* __restrict__ A12,
    float* __restrict__ G) {
  __shared__ float SA[K3B_NCH * 12];
  __shared__ float GL[320];
  int blk = blockIdx.x;                         // 8 b x 80 chunks
  int b = blk & 7;
  int n0 = (blk >> 3) * K3B_NCH;
  int tid = threadIdx.x;
  const float4* src = (const float4*)(A12 + (size_t)n0 * 12);
#pragma unroll
  for (int i = 0; i < 3; ++i)
    ((float4*)SA)[tid + i * 256] = src[tid + i * 256];
  for (int i = tid; i < 320; i += 256) GL[i] = 0.f;   // FIX: cover all 320
  __syncthreads();
  int wave = tid >> 6, lane = tid & 63;
  int c = lane & 31, nh = lane >> 5;
  float acc[10];
#pragma unroll
  for (int o = 0; o < 10; ++o) acc[o] = 0.f;
#pragma unroll 4
  for (int s = 0; s < K3B_NCH / 8; ++s) {
    int nl = s * 8 + wave * 2 + nh;
    float hv = h3[((size_t)b * N2 + n0 + nl) * 32 + c];
    const float4* ar = (const float4*)(SA + nl * 12);
    float4 a0 = ar[0], a1 = ar[1], a2 = ar[2];
    acc[0] += hv * a0.x; acc[1] += hv * a0.y;
    acc[2] += hv * a0.z; acc[3] += hv * a0.w;
    acc[4] += hv * a1.x; acc[5] += hv * a1.y;
    acc[6] += hv * a1.z; acc[7] += hv * a1.w;
    acc[8] += hv * a2.x; acc[9] += hv * a2.y;
  }
#pragma unroll
  for (int o = 0; o < 10; ++o) acc[o] += __shfl_xor(acc[o], 32);
  if (lane < 32) {
#pragma unroll
    for (int o = 0; o < 10; ++o) atomicAdd(&GL[c * 10 + o], acc[o]);
  }
  __syncthreads();
  for (int i = tid; i < 320; i += 256)                 // FIX: flush all 320
    atomicAdd(&G[b * 320 + i], GL[i]);
}

// ---- out[b][o] += (1/N2) * sum_{c,k} w3t[k][c][o] * G[b][c][k] ----
__global__ __launch_bounds__(256) void k3c(
    const float* __restrict__ G, const float* __restrict__ w3t,
    float* __restrict__ out) {
  int t = blockIdx.x * 256 + threadIdx.x;       // 2560 threads
  int pair = t >> 5, c = t & 31;
  int b = pair / 10, o = pair % 10;
  float s = 0.f;
#pragma unroll
  for (int k = 0; k < KC; ++k)
    s += G[b * 320 + c * 10 + k] * w3t[k * 320 + c * 10 + o];
#pragma unroll
  for (int off = 1; off < 32; off <<= 1) s += __shfl_xor(s, off);
  if ((threadIdx.x & 31) == 0) atomicAdd(&out[pair], s * (1.0f / N2));
}

extern "C" void kernel_launch(void* const* d_in, const int* in_sizes, int n_in,
                              void* d_out, int out_size, void* d_ws, size_t ws_size,
                              hipStream_t stream) {
  const float* x       = (const float*)d_in[0];
  const int*   conv_t0 = (const int*)d_in[1];
  const int*   conv_t1 = (const int*)d_in[2];
  const int*   conv_t2 = (const int*)d_in[3];
  const int*   adj0    = (const int*)d_in[4];
  const int*   adj1    = (const int*)d_in[5];
  const int*   pool0   = (const int*)d_in[6];
  const int*   pool1   = (const int*)d_in[7];
  const float* w1      = (const float*)d_in[8];
  const float* b1      = (const float*)d_in[9];
  const float* w2      = (const float*)d_in[10];
  const float* b2      = (const float*)d_in[11];
  const float* w3      = (const float*)d_in[12];
  const float* b3      = (const float*)d_in[13];
  float* out  = (float*)d_out;
  float* wsf  = (float*)d_ws;

  // words: region0 (xT12 15.7MB / h3 21MB alias) 5,242,880 | h2 5,242,880 |
  // fidxM 3,932,160 | fidxP 983,040 | A12 245,760 | G 2,560 | wB1 512 |
  // wB 2,560 | w3t 3,200  -> ~62.7 MB
  float* h3b   = wsf;
  uint4* xT12  = (uint4*)wsf;                   // aliases h3, dead after k1
  unsigned short* h2b = (unsigned short*)(wsf + 5242880);
  int* fidxM   = (int*)(wsf + 2 * 5242880);
  int* fidxP   = fidxM + (size_t)N1 * 4 * 12;
  float* A12   = (float*)(fidxP + (size_t)N2 * 4 * 12);
  float* G     = A12 + (size_t)N2 * 12;
  unsigned short* wB1 = (unsigned short*)(G + 2560);
  unsigned short* wB  = wB1 + 1024;
  float* w3t   = (float*)(wB + 5120);

  kprep<<<20, 256, 0, stream>>>(w1, w2, w3, b3, wB1, wB, w3t, G, out);
  ktransx<<<4 * (N0 / 4 / 256), 256, 0, stream>>>(x, xT12);
  kfidx<<<N1 * 4 / 256, 256, 0, stream>>>(conv_t0, conv_t1, adj0, adj1, pool0, pool1,
                                          fidxM, fidxP, A12);
  khist<<<N2 * 10 / 256, 256, 0, stream>>>(conv_t2, A12);
  k1<<<5120, 256, 0, stream>>>((const char*)xT12, fidxM, (const bf16x8*)wB1, b1, h2b);
  k2<<<1280, 256, 0, stream>>>((const char*)h2b, fidxP, (const bf16x8*)wB, b2, h3b);
  k3b<<<8 * (N2 / K3B_NCH), 256, 0, stream>>>(h3b, A12, G);
  k3c<<<10, 256, 0, stream>>>(G, w3t, out);
}

// Round 11
// 156.917 us; speedup vs baseline: 17.0622x; 1.0548x over previous
//
#include <hip/hip_runtime.h>

#define NB 8
#define CIN 3
#define N0 327680
#define N1 81920
#define N2 20480
#define KC 10
#define KA 4

typedef __attribute__((ext_vector_type(8))) short bf16x8;
typedef __attribute__((ext_vector_type(4))) float f32x4;
typedef uint4 __attribute__((aligned(4))) uint4_u;
typedef int4  __attribute__((aligned(4))) int4_u;

__device__ __forceinline__ unsigned f2bf(float f) {          // RNE float->bf16
  unsigned u = __float_as_uint(f);
  return (u + 0x7FFFu + ((u >> 16) & 1u)) >> 16;
}

union bfrag { bf16x8 v; unsigned u[4]; };

// ---- fused prep: blocks [0,1280) transx | [1280,2560) fidx | [2560,3360) hist |
// [3360,3380) weight-prep.  A12/G zeroed by hipMemsetAsync beforehand. ----
__global__ __launch_bounds__(256) void kpre(
    const float* __restrict__ x, uint4* __restrict__ xT12,
    const int* __restrict__ conv_t0, const int* __restrict__ conv_t1,
    const int* __restrict__ conv_t2,
    const int* __restrict__ adj0, const int* __restrict__ adj1,
    const int* __restrict__ pool0, const int* __restrict__ pool1,
    int* __restrict__ fidxM, int* __restrict__ fidxP, float* __restrict__ A12,
    const float* __restrict__ w1, const float* __restrict__ w2,
    const float* __restrict__ w3, const float* __restrict__ b3,
    unsigned short* __restrict__ wB1, unsigned short* __restrict__ wB,
    float* __restrict__ w3t, float* __restrict__ out) {
  int blk = blockIdx.x;
  if (blk < 1280) {
    // ---- x -> xT12 [bp][n][12B]: {b0c0|b0c1, b0c2|b1c0, b1c1|b1c2} bf16 ----
    int bp = blk & 3;
    int t = (blk >> 2) * 256 + threadIdx.x;     // handles n = 4t .. 4t+3
    int n = t * 4;
    const float* p0 = x + (size_t)(2 * bp) * CIN * N0 + n;
    const float* p1 = p0 + (size_t)CIN * N0;
    float4 a0 = *(const float4*)(p0);
    float4 a1 = *(const float4*)(p0 + N0);
    float4 a2 = *(const float4*)(p0 + 2 * N0);
    float4 c0 = *(const float4*)(p1);
    float4 c1 = *(const float4*)(p1 + N0);
    float4 c2 = *(const float4*)(p1 + 2 * N0);
    unsigned w[12];
    const float* A0 = &a0.x; const float* A1 = &a1.x; const float* A2 = &a2.x;
    const float* C0 = &c0.x; const float* C1 = &c1.x; const float* C2 = &c2.x;
#pragma unroll
    for (int r = 0; r < 4; ++r) {
      w[r * 3 + 0] = f2bf(A0[r]) | (f2bf(A1[r]) << 16);
      w[r * 3 + 1] = f2bf(A2[r]) | (f2bf(C0[r]) << 16);
      w[r * 3 + 2] = f2bf(C1[r]) | (f2bf(C2[r]) << 16);
    }
    uint4* dst = xT12 + ((size_t)bp * N0 / 4 + t) * 3;
    dst[0] = make_uint4(w[0], w[1], w[2], w[3]);
    dst[1] = make_uint4(w[4], w[5], w[6], w[7]);
    dst[2] = make_uint4(w[8], w[9], w[10], w[11]);
  } else if (blk < 2560) {
    // ---- index tables ----
    // fidxM row (48B): [t0 t1 t8 t9 | t2 t3 t4 t5 | t6 t7 0 0]  (byte offs, x12)
    // fidxP row (48B): [e0 e2 e4 e6 | e8 0 o1 o3 | o5 o7 o9 0]  (byte offs, x32)
    int t = (blk - 1280) * 256 + threadIdx.x;   // N1*4 threads
    int j = t >> 2, p = t & 3;
    int pj = pool0[j];
    int pos = adj0[pj * KA + p];
    const int2* s0 = (const int2*)(conv_t0 + (size_t)pos * 10);
    int2 q0 = s0[0], q1 = s0[1], q2 = s0[2], q3 = s0[3], q4 = s0[4];
    int4_u* dM = (int4_u*)(fidxM + (size_t)t * 12);
    dM[0] = make_int4(q0.x * 12, q0.y * 12, q4.x * 12, q4.y * 12);
    dM[1] = make_int4(q1.x * 12, q1.y * 12, q2.x * 12, q2.y * 12);
    dM[2] = make_int4(q3.x * 12, q3.y * 12, 0, 0);
    if (j < N2) {
      int qj = pool1[j];
      int qos = adj1[qj * KA + p];
      const int2* s1 = (const int2*)(conv_t1 + (size_t)qos * 10);
      int2 r0 = s1[0], r1 = s1[1], r2 = s1[2], r3 = s1[3], r4 = s1[4];
      int4_u* dP = (int4_u*)(fidxP + (size_t)t * 12);
      dP[0] = make_int4(r0.x * 32, r1.x * 32, r2.x * 32, r3.x * 32);
      dP[1] = make_int4(r4.x * 32, 0,          r0.y * 32, r1.y * 32);
      dP[2] = make_int4(r2.y * 32, r3.y * 32, r4.y * 32, 0);
    }
  } else if (blk < 3360) {
    // ---- histogram A[n][k] = #{j: conv_t2[j,k] = n} ----
    int t = (blk - 2560) * 256 + threadIdx.x;   // N2*10 threads
    int n = conv_t2[t];
    int k = t % 10;
    atomicAdd(&A12[n * 12 + k], 1.0f);
  } else {
    // ---- weight prep ----
    int t = (blk - 3360) * 256 + threadIdx.x;
    if (t < 1024) {
      int ch = t >> 9, rest = t & 511, l = rest >> 3, e = rest & 7;
      int k = ch * 32 + ((l >> 4) * 8) + e;
      int tap = k >> 2, cc = k & 3;
      float v = (tap < KC && cc < CIN) ? w1[((l & 15) * CIN + cc) * KC + tap] : 0.f;
      wB1[t] = (unsigned short)f2bf(v);
    }
    if (t < 5120) {
      int e = t & 7, l = (t >> 3) & 63, nt = (t >> 9) & 1, q = t >> 10;
      int kc = q * 32 + ((l >> 4) * 8) + e;
      int tap = kc >> 4, c = kc & 15;
      int o = nt * 16 + (l & 15);
      wB[t] = (unsigned short)f2bf(w2[(o * 16 + c) * KC + tap]);
    }
    if (t < 3200) { int o = t % 10, r = t / 10, c = r & 31, k = r >> 5;
                    w3t[t] = w3[(o * 32 + c) * KC + k]; }
    if (t < 80)   out[t] = b3[t % 10];
  }
}

// ---- conv1 (3->16) + maxpool0 via MFMA gather-GEMM ----
// sched_barrier pins all 4 idx + 16 gathers in flight before any MFMA.
__global__ __launch_bounds__(256, 4) void k1(
    const char* __restrict__ xT12, const int* __restrict__ fidxM,
    const bf16x8* __restrict__ wB1, const float* __restrict__ b1,
    unsigned short* __restrict__ h2) {
  int blk = blockIdx.x;
  int bp = blk & 3;                             // batch pair, XCD-pinned
  int wave = threadIdx.x >> 6;
  int lane = threadIdx.x & 63;
  int col = lane & 15, hi = lane >> 4;
  int tile0 = ((blk >> 2) * 4 + wave) * 4;      // 4 tiles/wave
  const char* xb = xT12 + (size_t)bp * N0 * 12;
  unsigned short* h2b0 = h2 + (size_t)(2 * bp) * N1 * 16;
  unsigned short* h2b1 = h2b0 + (size_t)N1 * 16;
  bf16x8 B0 = wB1[lane];
  bf16x8 B1 = wB1[64 + lane];
  float bias = b1[col];
  int seloff = ((hi + 1) >> 1) << 2;            // ints: hi->{0,4,4,8}

  int4 I[4];
#pragma unroll
  for (int i = 0; i < 4; ++i)
    I[i] = *(const int4_u*)(fidxM + ((size_t)(tile0 + i) * 16 + col) * 12 + seloff);

  uint4 g[4][4];
#pragma unroll
  for (int i = 0; i < 4; ++i) {
    int a0 = (hi == 2) ? I[i].z : I[i].x;       // taps {2hi, 2hi+1}
    int a1 = (hi == 2) ? I[i].w : I[i].y;
    int a2 = (hi == 0) ? I[i].z : 0;            // taps {8,9} (hi=0 only)
    int a3 = (hi == 0) ? I[i].w : 0;
    g[i][0] = *(const uint4_u*)(xb + a0);
    g[i][1] = *(const uint4_u*)(xb + a1);
    g[i][2] = *(const uint4_u*)(xb + a2);
    g[i][3] = *(const uint4_u*)(xb + a3);
  }
  __builtin_amdgcn_sched_barrier(0);            // keep all 16 gathers in flight

#pragma unroll
  for (int i = 0; i < 4; ++i) {
    uint4 g0 = g[i][0], g1 = g[i][1], g2 = g[i][2], g3 = g[i][3];
    bfrag A0c0, A1c0, A0c1, A1c1;
    A0c0.u[0] = g0.x; A0c0.u[1] = g0.y & 0xFFFFu;
    A0c0.u[2] = g1.x; A0c0.u[3] = g1.y & 0xFFFFu;
    A1c0.u[0] = (g0.y >> 16) | (g0.z << 16); A1c0.u[1] = g0.z >> 16;
    A1c0.u[2] = (g1.y >> 16) | (g1.z << 16); A1c0.u[3] = g1.z >> 16;
    A0c1.u[0] = g2.x; A0c1.u[1] = g2.y & 0xFFFFu;
    A0c1.u[2] = g3.x; A0c1.u[3] = g3.y & 0xFFFFu;
    A1c1.u[0] = (g2.y >> 16) | (g2.z << 16); A1c1.u[1] = g2.z >> 16;
    A1c1.u[2] = (g3.y >> 16) | (g3.z << 16); A1c1.u[3] = g3.z >> 16;
    f32x4 z = {0.f, 0.f, 0.f, 0.f};
    f32x4 acc0 = __builtin_amdgcn_mfma_f32_16x16x32_bf16(A0c0.v, B0, z, 0, 0, 0);
    acc0 = __builtin_amdgcn_mfma_f32_16x16x32_bf16(A0c1.v, B1, acc0, 0, 0, 0);
    f32x4 acc1 = __builtin_amdgcn_mfma_f32_16x16x32_bf16(A1c0.v, B0, z, 0, 0, 0);
    acc1 = __builtin_amdgcn_mfma_f32_16x16x32_bf16(A1c1.v, B1, acc1, 0, 0, 0);
    float m0 = fmaxf(fmaxf(acc0[0], acc0[1]), fmaxf(acc0[2], acc0[3])) + bias;
    float m1 = fmaxf(fmaxf(acc1[0], acc1[1]), fmaxf(acc1[2], acc1[3])) + bias;
    size_t j = (size_t)(tile0 + i) * 4 + hi;
    h2b0[j * 16 + col] = (unsigned short)f2bf(m0);
    h2b1[j * 16 + col] = (unsigned short)f2bf(m1);
  }
}

// ---- conv2 (16->32) + maxpool1 via MFMA gather-GEMM; 2 idx + 5 gathers per tile ----
__global__ __launch_bounds__(256) void k2(
    const char* __restrict__ h2, const int* __restrict__ fidxP,
    const bf16x8* __restrict__ wB, const float* __restrict__ b2,
    float* __restrict__ h3) {
  int blk = blockIdx.x;
  int b = blk & 7;
  int wave = threadIdx.x >> 6;
  int lane = threadIdx.x & 63;
  int col = lane & 15;
  int odd = (lane >> 5) & 1;
  int tile0 = ((blk >> 3) * 4 + wave) * 8;
  const char* hb = h2 + (size_t)b * N1 * 32 + ((lane >> 4) & 1) * 16;

  bf16x8 Bf[10];
#pragma unroll
  for (int i = 0; i < 10; ++i) Bf[i] = wB[i * 64 + lane];
  float bias0 = b2[col];
  float bias1 = b2[16 + col];

#pragma unroll 2
  for (int i = 0; i < 8; ++i) {
    int tile = tile0 + i;
    const int* fp = fidxP + ((size_t)tile * 16 + col) * 12 + odd * 6;
    int4 T = *(const int4_u*)fp;                // 4 taps of my parity
    int  T4 = fp[4];                            // 5th tap
    f32x4 acc0 = {0.f, 0.f, 0.f, 0.f};
    f32x4 acc1 = {0.f, 0.f, 0.f, 0.f};
    bf16x8 A;
    A = *(const bf16x8*)(hb + T.x);
    acc0 = __builtin_amdgcn_mfma_f32_16x16x32_bf16(A, Bf[0], acc0, 0, 0, 0);
    acc1 = __builtin_amdgcn_mfma_f32_16x16x32_bf16(A, Bf[1], acc1, 0, 0, 0);
    A = *(const bf16x8*)(hb + T.y);
    acc0 = __builtin_amdgcn_mfma_f32_16x16x32_bf16(A, Bf[2], acc0, 0, 0, 0);
    acc1 = __builtin_amdgcn_mfma_f32_16x16x32_bf16(A, Bf[3], acc1, 0, 0, 0);
    A = *(const bf16x8*)(hb + T.z);
    acc0 = __builtin_amdgcn_mfma_f32_16x16x32_bf16(A, Bf[4], acc0, 0, 0, 0);
    acc1 = __builtin_amdgcn_mfma_f32_16x16x32_bf16(A, Bf[5], acc1, 0, 0, 0);
    A = *(const bf16x8*)(hb + T.w);
    acc0 = __builtin_amdgcn_mfma_f32_16x16x32_bf16(A, Bf[6], acc0, 0, 0, 0);
    acc1 = __builtin_amdgcn_mfma_f32_16x16x32_bf16(A, Bf[7], acc1, 0, 0, 0);
    A = *(const bf16x8*)(hb + T4);
    acc0 = __builtin_amdgcn_mfma_f32_16x16x32_bf16(A, Bf[8], acc0, 0, 0, 0);
    acc1 = __builtin_amdgcn_mfma_f32_16x16x32_bf16(A, Bf[9], acc1, 0, 0, 0);
    float m0 = fmaxf(fmaxf(acc0[0], acc0[1]), fmaxf(acc0[2], acc0[3])) + bias0;
    float m1 = fmaxf(fmaxf(acc1[0], acc1[1]), fmaxf(acc1[2], acc1[3])) + bias1;
    int j = tile * 4 + (lane >> 4);
    float* dst = h3 + ((size_t)b * N2 + j) * 32 + col;
    dst[0]  = m0;
    dst[16] = m1;
  }
}

// ---- G[b][c][k] = sum_n A[n][k] * h3[b][n][c] : sequential h3 stream ----
#define K3B_NCH 256
__global__ __launch_bounds__(256) void k3b(
    const float* __restrict__ h3, const float* __restrict__ A12,
    float* __restrict__ G) {
  __shared__ float SA[K3B_NCH * 12];
  __shared__ float GL[320];
  int blk = blockIdx.x;                         // 8 b x 80 chunks
  int b = blk & 7;
  int n0 = (blk >> 3) * K3B_NCH;
  int tid = threadIdx.x;
  const float4* src = (const float4*)(A12 + (size_t)n0 * 12);
#pragma unroll
  for (int i = 0; i < 3; ++i)
    ((float4*)SA)[tid + i * 256] = src[tid + i * 256];
  for (int i = tid; i < 320; i += 256) GL[i] = 0.f;
  __syncthreads();
  int wave = tid >> 6, lane = tid & 63;
  int c = lane & 31, nh = lane >> 5;
  float acc[10];
#pragma unroll
  for (int o = 0; o < 10; ++o) acc[o] = 0.f;
#pragma unroll 4
  for (int s = 0; s < K3B_NCH / 8; ++s) {
    int nl = s * 8 + wave * 2 + nh;
    float hv = h3[((size_t)b * N2 + n0 + nl) * 32 + c];
    const float4* ar = (const float4*)(SA + nl * 12);
    float4 a0 = ar[0], a1 = ar[1], a2 = ar[2];
    acc[0] += hv * a0.x; acc[1] += hv * a0.y;
    acc[2] += hv * a0.z; acc[3] += hv * a0.w;
    acc[4] += hv * a1.x; acc[5] += hv * a1.y;
    acc[6] += hv * a1.z; acc[7] += hv * a1.w;
    acc[8] += hv * a2.x; acc[9] += hv * a2.y;
  }
#pragma unroll
  for (int o = 0; o < 10; ++o) acc[o] += __shfl_xor(acc[o], 32);
  if (lane < 32) {
#pragma unroll
    for (int o = 0; o < 10; ++o) atomicAdd(&GL[c * 10 + o], acc[o]);
  }
  __syncthreads();
  for (int i = tid; i < 320; i += 256)
    atomicAdd(&G[b * 320 + i], GL[i]);
}

// ---- out[b][o] += (1/N2) * sum_{c,k} w3t[k][c][o] * G[b][c][k] ----
__global__ __launch_bounds__(256) void k3c(
    const float* __restrict__ G, const float* __restrict__ w3t,
    float* __restrict__ out) {
  int t = blockIdx.x * 256 + threadIdx.x;       // 2560 threads
  int pair = t >> 5, c = t & 31;
  int b = pair / 10, o = pair % 10;
  float s = 0.f;
#pragma unroll
  for (int k = 0; k < KC; ++k)
    s += G[b * 320 + c * 10 + k] * w3t[k * 320 + c * 10 + o];
#pragma unroll
  for (int off = 1; off < 32; off <<= 1) s += __shfl_xor(s, off);
  if ((threadIdx.x & 31) == 0) atomicAdd(&out[pair], s * (1.0f / N2));
}

extern "C" void kernel_launch(void* const* d_in, const int* in_sizes, int n_in,
                              void* d_out, int out_size, void* d_ws, size_t ws_size,
                              hipStream_t stream) {
  const float* x       = (const float*)d_in[0];
  const int*   conv_t0 = (const int*)d_in[1];
  const int*   conv_t1 = (const int*)d_in[2];
  const int*   conv_t2 = (const int*)d_in[3];
  const int*   adj0    = (const int*)d_in[4];
  const int*   adj1    = (const int*)d_in[5];
  const int*   pool0   = (const int*)d_in[6];
  const int*   pool1   = (const int*)d_in[7];
  const float* w1      = (const float*)d_in[8];
  const float* b1      = (const float*)d_in[9];
  const float* w2      = (const float*)d_in[10];
  const float* b2      = (const float*)d_in[11];
  const float* w3      = (const float*)d_in[12];
  const float* b3      = (const float*)d_in[13];
  float* out  = (float*)d_out;
  float* wsf  = (float*)d_ws;

  // words: region0 (xT12 15.7MB / h3 21MB alias) 5,242,880 | h2 5,242,880 |
  // fidxM 3,932,160 | fidxP 983,040 | A12 245,760 | G 2,560 | wB1 512 |
  // wB 2,560 | w3t 3,200  -> ~62.7 MB
  float* h3b   = wsf;
  uint4* xT12  = (uint4*)wsf;                   // aliases h3, dead after k1
  unsigned short* h2b = (unsigned short*)(wsf + 5242880);
  int* fidxM   = (int*)(wsf + 2 * 5242880);
  int* fidxP   = fidxM + (size_t)N1 * 4 * 12;
  float* A12   = (float*)(fidxP + (size_t)N2 * 4 * 12);
  float* G     = A12 + (size_t)N2 * 12;
  unsigned short* wB1 = (unsigned short*)(G + 2560);
  unsigned short* wB  = wB1 + 1024;
  float* w3t   = (float*)(wB + 5120);

  hipMemsetAsync(A12, 0, (size_t)(N2 * 12 + 2560) * 4, stream);  // A12 + G
  kpre<<<3380, 256, 0, stream>>>(x, xT12, conv_t0, conv_t1, conv_t2,
                                 adj0, adj1, pool0, pool1,
                                 fidxM, fidxP, A12,
                                 w1, w2, w3, b3, wB1, wB, w3t, out);
  k1<<<5120, 256, 0, stream>>>((const char*)xT12, fidxM, (const bf16x8*)wB1, b1, h2b);
  k2<<<1280, 256, 0, stream>>>((const char*)h2b, fidxP, (const bf16x8*)wB, b2, h3b);
  k3b<<<8 * (N2 / K3B_NCH), 256, 0, stream>>>(h3b, A12, G);
  k3c<<<10, 256, 0, stream>>>(G, w3t, out);
}

// Round 12
// 154.597 us; speedup vs baseline: 17.3182x; 1.0150x over previous
//
#include <hip/hip_runtime.h>

#define NB 8
#define CIN 3
#define N0 327680
#define N1 81920
#define N2 20480
#define KC 10
#define KA 4

typedef __attribute__((ext_vector_type(8))) short bf16x8;
typedef __attribute__((ext_vector_type(4))) float f32x4;
typedef int4  __attribute__((aligned(4))) int4_u;

__device__ __forceinline__ unsigned f2bf(float f) {          // RNE float->bf16
  unsigned u = __float_as_uint(f);
  return (u + 0x7FFFu + ((u >> 16) & 1u)) >> 16;
}

union bfrag { bf16x8 v; unsigned u[4]; };

// ---- fused prep: blocks [0,1280) transx | [1280,2560) fidx | [2560,3360) hist |
// [3360,3380) weight-prep.  A12/G zeroed by hipMemsetAsync beforehand. ----
__global__ __launch_bounds__(256) void kpre(
    const float* __restrict__ x, uint4* __restrict__ xT64,
    const int* __restrict__ conv_t0, const int* __restrict__ conv_t1,
    const int* __restrict__ conv_t2,
    const int* __restrict__ adj0, const int* __restrict__ adj1,
    const int* __restrict__ pool0, const int* __restrict__ pool1,
    int* __restrict__ fidxM, int* __restrict__ fidxP, float* __restrict__ A12,
    const float* __restrict__ w1, const float* __restrict__ w2,
    const float* __restrict__ w3, const float* __restrict__ b3,
    unsigned short* __restrict__ wB1, unsigned short* __restrict__ wB,
    float* __restrict__ w3t, float* __restrict__ out) {
  int blk = blockIdx.x;
  if (blk < 1280) {
    // ---- x -> xT64 [n][64B]: 4 bpair-triples {c0|c1, c2|c0', c1'|c2'} + 16B pad ----
    int n = blk * 256 + threadIdx.x;
    unsigned d[12];
#pragma unroll
    for (int bp = 0; bp < 4; ++bp) {
      const float* pe = x + (size_t)(2 * bp) * CIN * N0 + n;       // even batch
      const float* po = pe + (size_t)CIN * N0;                    // odd batch
      float e0 = pe[0], e1 = pe[N0], e2 = pe[2 * N0];
      float o0 = po[0], o1 = po[N0], o2 = po[2 * N0];
      d[bp * 3 + 0] = f2bf(e0) | (f2bf(e1) << 16);
      d[bp * 3 + 1] = f2bf(e2) | (f2bf(o0) << 16);
      d[bp * 3 + 2] = f2bf(o1) | (f2bf(o2) << 16);
    }
    uint4* dst = xT64 + (size_t)n * 4;
    dst[0] = make_uint4(d[0], d[1], d[2], d[3]);
    dst[1] = make_uint4(d[4], d[5], d[6], d[7]);
    dst[2] = make_uint4(d[8], d[9], d[10], d[11]);
    dst[3] = make_uint4(0, 0, 0, 0);
  } else if (blk < 2560) {
    // ---- index tables ----
    // fidxM row (48B): [t0 t1 t8 t9 | t2 t3 t4 t5 | t6 t7 0 0]  (byte offs, x64)
    // fidxP row (48B): [e0 e2 e4 e6 | e8 0 o1 o3 | o5 o7 o9 0]  (byte offs, x32)
    int t = (blk - 1280) * 256 + threadIdx.x;   // N1*4 threads
    int j = t >> 2, p = t & 3;
    int pj = pool0[j];
    int pos = adj0[pj * KA + p];
    const int2* s0 = (const int2*)(conv_t0 + (size_t)pos * 10);
    int2 q0 = s0[0], q1 = s0[1], q2 = s0[2], q3 = s0[3], q4 = s0[4];
    int4_u* dM = (int4_u*)(fidxM + (size_t)t * 12);
    dM[0] = make_int4(q0.x * 64, q0.y * 64, q4.x * 64, q4.y * 64);
    dM[1] = make_int4(q1.x * 64, q1.y * 64, q2.x * 64, q2.y * 64);
    dM[2] = make_int4(q3.x * 64, q3.y * 64, 0, 0);
    if (j < N2) {
      int qj = pool1[j];
      int qos = adj1[qj * KA + p];
      const int2* s1 = (const int2*)(conv_t1 + (size_t)qos * 10);
      int2 r0 = s1[0], r1 = s1[1], r2 = s1[2], r3 = s1[3], r4 = s1[4];
      int4_u* dP = (int4_u*)(fidxP + (size_t)t * 12);
      dP[0] = make_int4(r0.x * 32, r1.x * 32, r2.x * 32, r3.x * 32);
      dP[1] = make_int4(r4.x * 32, 0,          r0.y * 32, r1.y * 32);
      dP[2] = make_int4(r2.y * 32, r3.y * 32, r4.y * 32, 0);
    }
  } else if (blk < 3360) {
    // ---- histogram A[n][k] = #{j: conv_t2[j,k] = n} ----
    int t = (blk - 2560) * 256 + threadIdx.x;   // N2*10 threads
    int n = conv_t2[t];
    int k = t % 10;
    atomicAdd(&A12[n * 12 + k], 1.0f);
  } else {
    // ---- weight prep ----
    int t = (blk - 3360) * 256 + threadIdx.x;
    if (t < 1024) {
      int ch = t >> 9, rest = t & 511, l = rest >> 3, e = rest & 7;
      int k = ch * 32 + ((l >> 4) * 8) + e;
      int tap = k >> 2, cc = k & 3;
      float v = (tap < KC && cc < CIN) ? w1[((l & 15) * CIN + cc) * KC + tap] : 0.f;
      wB1[t] = (unsigned short)f2bf(v);
    }
    if (t < 5120) {
      int e = t & 7, l = (t >> 3) & 63, nt = (t >> 9) & 1, q = t >> 10;
      int kc = q * 32 + ((l >> 4) * 8) + e;
      int tap = kc >> 4, c = kc & 15;
      int o = nt * 16 + (l & 15);
      wB[t] = (unsigned short)f2bf(w2[(o * 16 + c) * KC + tap]);
    }
    if (t < 3200) { int o = t % 10, r = t / 10, c = r & 31, k = r >> 5;
                    w3t[t] = w3[(o * 32 + c) * KC + k]; }
    if (t < 80)   out[t] = b3[t % 10];
  }
}

// dword triple of bpair s (s compile-time) from a 12-dword row (Ra,Rb,Rc)
#define TR0(s) ((s) == 0 ? Ra.x : (s) == 1 ? Ra.w : (s) == 2 ? Rb.z : Rc.y)
#define TR1(s) ((s) == 0 ? Ra.y : (s) == 1 ? Rb.x : (s) == 2 ? Rb.w : Rc.z)
#define TR2(s) ((s) == 0 ? Ra.z : (s) == 1 ? Rb.y : (s) == 2 ? Rc.x : Rc.w)

// ---- conv1 (3->16) + maxpool0 via MFMA gather-GEMM, one 64B line per (jp,tap)
// serves ALL 8 batches. Tile = 16 jp rows; lane=(col,hi); taps {2hi,2hi+1} +
// {8,9 on hi=0, B1 rows >=40 are zero}. D regs = 4 pool cands of j=tile*4+hi. ----
__global__ __launch_bounds__(256) void k1(
    const char* __restrict__ xT64, const int* __restrict__ fidxM,
    const bf16x8* __restrict__ wB1, const float* __restrict__ b1,
    unsigned short* __restrict__ h2) {
  int blk = blockIdx.x;
  int wave = threadIdx.x >> 6;
  int lane = threadIdx.x & 63;
  int col = lane & 15, hi = lane >> 4;
  int tile0 = (blk * 4 + wave) * 4;             // 4 tiles/wave; 20480 tiles
  bf16x8 B0 = wB1[lane];
  bf16x8 B1 = wB1[64 + lane];
  float bias = b1[col];
  int seloff = ((hi + 1) >> 1) << 2;            // ints: hi->{0,4,4,8}

#pragma unroll
  for (int i = 0; i < 4; ++i) {
    int tile = tile0 + i;
    int4 I = *(const int4_u*)(fidxM + ((size_t)tile * 16 + col) * 12 + seloff);
    int a0 = (hi == 2) ? I.z : I.x;             // tap 2hi
    int a1 = (hi == 2) ? I.w : I.y;             // tap 2hi+1
    int a2 = (hi == 0) ? I.z : 0;               // tap 8 (hi=0 only; else dummy)
    int a3 = (hi == 0) ? I.w : 0;               // tap 9
    const uint4* r0p = (const uint4*)(xT64 + a0);
    const uint4* r1p = (const uint4*)(xT64 + a1);
    const uint4* r2p = (const uint4*)(xT64 + a2);
    const uint4* r3p = (const uint4*)(xT64 + a3);
    uint4 R0a = r0p[0], R0b = r0p[1], R0c = r0p[2];
    uint4 R1a = r1p[0], R1b = r1p[1], R1c = r1p[2];
    uint4 R2a = r2p[0], R2b = r2p[1], R2c = r2p[2];
    uint4 R3a = r3p[0], R3b = r3p[1], R3c = r3p[2];
    size_t j = (size_t)tile * 4 + hi;
    unsigned short* dst = h2 + j * 16 + col;

#define DO_BPAIR(s)                                                           \
    {                                                                         \
      unsigned t0, t1, t2, u0, u1, u2, v0, v1, v2, w0, w1, w2;                \
      { uint4 Ra = R0a, Rb = R0b, Rc = R0c;                                   \
        t0 = TR0(s); t1 = TR1(s); t2 = TR2(s); }                              \
      { uint4 Ra = R1a, Rb = R1b, Rc = R1c;                                   \
        u0 = TR0(s); u1 = TR1(s); u2 = TR2(s); }                              \
      { uint4 Ra = R2a, Rb = R2b, Rc = R2c;                                   \
        v0 = TR0(s); v1 = TR1(s); v2 = TR2(s); }                              \
      { uint4 Ra = R3a, Rb = R3b, Rc = R3c;                                   \
        w0 = TR0(s); w1 = TR1(s); w2 = TR2(s); }                              \
      bfrag A0c0, A1c0, A0c1, A1c1;                                           \
      A0c0.u[0] = t0; A0c0.u[1] = t1 & 0xFFFFu;                               \
      A0c0.u[2] = u0; A0c0.u[3] = u1 & 0xFFFFu;                               \
      A1c0.u[0] = (t1 >> 16) | (t2 << 16); A1c0.u[1] = t2 >> 16;              \
      A1c0.u[2] = (u1 >> 16) | (u2 << 16); A1c0.u[3] = u2 >> 16;              \
      A0c1.u[0] = v0; A0c1.u[1] = v1 & 0xFFFFu;                               \
      A0c1.u[2] = w0; A0c1.u[3] = w1 & 0xFFFFu;                               \
      A1c1.u[0] = (v1 >> 16) | (v2 << 16); A1c1.u[1] = v2 >> 16;              \
      A1c1.u[2] = (w1 >> 16) | (w2 << 16); A1c1.u[3] = w2 >> 16;              \
      f32x4 z = {0.f, 0.f, 0.f, 0.f};                                         \
      f32x4 acc0 = __builtin_amdgcn_mfma_f32_16x16x32_bf16(A0c0.v, B0, z, 0, 0, 0); \
      acc0 = __builtin_amdgcn_mfma_f32_16x16x32_bf16(A0c1.v, B1, acc0, 0, 0, 0);    \
      f32x4 acc1 = __builtin_amdgcn_mfma_f32_16x16x32_bf16(A1c0.v, B0, z, 0, 0, 0); \
      acc1 = __builtin_amdgcn_mfma_f32_16x16x32_bf16(A1c1.v, B1, acc1, 0, 0, 0);    \
      float m0 = fmaxf(fmaxf(acc0[0], acc0[1]), fmaxf(acc0[2], acc0[3])) + bias;    \
      float m1 = fmaxf(fmaxf(acc1[0], acc1[1]), fmaxf(acc1[2], acc1[3])) + bias;    \
      dst[(size_t)(2 * (s)) * N1 * 16]     = (unsigned short)f2bf(m0);        \
      dst[(size_t)(2 * (s) + 1) * N1 * 16] = (unsigned short)f2bf(m1);        \
    }
    DO_BPAIR(0)
    DO_BPAIR(1)
    DO_BPAIR(2)
    DO_BPAIR(3)
#undef DO_BPAIR
  }
}

// ---- conv2 (16->32) + maxpool1 via MFMA gather-GEMM; 2 idx + 5 gathers per tile ----
__global__ __launch_bounds__(256) void k2(
    const char* __restrict__ h2, const int* __restrict__ fidxP,
    const bf16x8* __restrict__ wB, const float* __restrict__ b2,
    float* __restrict__ h3) {
  int blk = blockIdx.x;
  int b = blk & 7;
  int wave = threadIdx.x >> 6;
  int lane = threadIdx.x & 63;
  int col = lane & 15;
  int odd = (lane >> 5) & 1;
  int tile0 = ((blk >> 3) * 4 + wave) * 8;
  const char* hb = h2 + (size_t)b * N1 * 32 + ((lane >> 4) & 1) * 16;

  bf16x8 Bf[10];
#pragma unroll
  for (int i = 0; i < 10; ++i) Bf[i] = wB[i * 64 + lane];
  float bias0 = b2[col];
  float bias1 = b2[16 + col];

#pragma unroll 2
  for (int i = 0; i < 8; ++i) {
    int tile = tile0 + i;
    const int* fp = fidxP + ((size_t)tile * 16 + col) * 12 + odd * 6;
    int4 T = *(const int4_u*)fp;                // 4 taps of my parity
    int  T4 = fp[4];                            // 5th tap
    f32x4 acc0 = {0.f, 0.f, 0.f, 0.f};
    f32x4 acc1 = {0.f, 0.f, 0.f, 0.f};
    bf16x8 A;
    A = *(const bf16x8*)(hb + T.x);
    acc0 = __builtin_amdgcn_mfma_f32_16x16x32_bf16(A, Bf[0], acc0, 0, 0, 0);
    acc1 = __builtin_amdgcn_mfma_f32_16x16x32_bf16(A, Bf[1], acc1, 0, 0, 0);
    A = *(const bf16x8*)(hb + T.y);
    acc0 = __builtin_amdgcn_mfma_f32_16x16x32_bf16(A, Bf[2], acc0, 0, 0, 0);
    acc1 = __builtin_amdgcn_mfma_f32_16x16x32_bf16(A, Bf[3], acc1, 0, 0, 0);
    A = *(const bf16x8*)(hb + T.z);
    acc0 = __builtin_amdgcn_mfma_f32_16x16x32_bf16(A, Bf[4], acc0, 0, 0, 0);
    acc1 = __builtin_amdgcn_mfma_f32_16x16x32_bf16(A, Bf[5], acc1, 0, 0, 0);
    A = *(const bf16x8*)(hb + T.w);
    acc0 = __builtin_amdgcn_mfma_f32_16x16x32_bf16(A, Bf[6], acc0, 0, 0, 0);
    acc1 = __builtin_amdgcn_mfma_f32_16x16x32_bf16(A, Bf[7], acc1, 0, 0, 0);
    A = *(const bf16x8*)(hb + T4);
    acc0 = __builtin_amdgcn_mfma_f32_16x16x32_bf16(A, Bf[8], acc0, 0, 0, 0);
    acc1 = __builtin_amdgcn_mfma_f32_16x16x32_bf16(A, Bf[9], acc1, 0, 0, 0);
    float m0 = fmaxf(fmaxf(acc0[0], acc0[1]), fmaxf(acc0[2], acc0[3])) + bias0;
    float m1 = fmaxf(fmaxf(acc1[0], acc1[1]), fmaxf(acc1[2], acc1[3])) + bias1;
    int j = tile * 4 + (lane >> 4);
    float* dst = h3 + ((size_t)b * N2 + j) * 32 + col;
    dst[0]  = m0;
    dst[16] = m1;
  }
}

// ---- G[b][c][k] = sum_n A[n][k] * h3[b][n][c] : sequential h3 stream ----
#define K3B_NCH 256
__global__ __launch_bounds__(256) void k3b(
    const float* __restrict__ h3, const float* __restrict__ A12,
    float* __restrict__ G) {
  __shared__ float SA[K3B_NCH * 12];
  __shared__ float GL[320];
  int blk = blockIdx.x;                         // 8 b x 80 chunks
  int b = blk & 7;
  int n0 = (blk >> 3) * K3B_NCH;
  int tid = threadIdx.x;
  const float4* src = (const float4*)(A12 + (size_t)n0 * 12);
#pragma unroll
  for (int i = 0; i < 3; ++i)
    ((float4*)SA)[tid + i * 256] = src[tid + i * 256];
  for (int i = tid; i < 320; i += 256) GL[i] = 0.f;
  __syncthreads();
  int wave = tid >> 6, lane = tid & 63;
  int c = lane & 31, nh = lane >> 5;
  float acc[10];
#pragma unroll
  for (int o = 0; o < 10; ++o) acc[o] = 0.f;
#pragma unroll 4
  for (int s = 0; s < K3B_NCH / 8; ++s) {
    int nl = s * 8 + wave * 2 + nh;
    float hv = h3[((size_t)b * N2 + n0 + nl) * 32 + c];
    const float4* ar = (const float4*)(SA + nl * 12);
    float4 a0 = ar[0], a1 = ar[1], a2 = ar[2];
    acc[0] += hv * a0.x; acc[1] += hv * a0.y;
    acc[2] += hv * a0.z; acc[3] += hv * a0.w;
    acc[4] += hv * a1.x; acc[5] += hv * a1.y;
    acc[6] += hv * a1.z; acc[7] += hv * a1.w;
    acc[8] += hv * a2.x; acc[9] += hv * a2.y;
  }
#pragma unroll
  for (int o = 0; o < 10; ++o) acc[o] += __shfl_xor(acc[o], 32);
  if (lane < 32) {
#pragma unroll
    for (int o = 0; o < 10; ++o) atomicAdd(&GL[c * 10 + o], acc[o]);
  }
  __syncthreads();
  for (int i = tid; i < 320; i += 256)
    atomicAdd(&G[b * 320 + i], GL[i]);
}

// ---- out[b][o] += (1/N2) * sum_{c,k} w3t[k][c][o] * G[b][c][k] ----
__global__ __launch_bounds__(256) void k3c(
    const float* __restrict__ G, const float* __restrict__ w3t,
    float* __restrict__ out) {
  int t = blockIdx.x * 256 + threadIdx.x;       // 2560 threads
  int pair = t >> 5, c = t & 31;
  int b = pair / 10, o = pair % 10;
  float s = 0.f;
#pragma unroll
  for (int k = 0; k < KC; ++k)
    s += G[b * 320 + c * 10 + k] * w3t[k * 320 + c * 10 + o];
#pragma unroll
  for (int off = 1; off < 32; off <<= 1) s += __shfl_xor(s, off);
  if ((threadIdx.x & 31) == 0) atomicAdd(&out[pair], s * (1.0f / N2));
}

extern "C" void kernel_launch(void* const* d_in, const int* in_sizes, int n_in,
                              void* d_out, int out_size, void* d_ws, size_t ws_size,
                              hipStream_t stream) {
  const float* x       = (const float*)d_in[0];
  const int*   conv_t0 = (const int*)d_in[1];
  const int*   conv_t1 = (const int*)d_in[2];
  const int*   conv_t2 = (const int*)d_in[3];
  const int*   adj0    = (const int*)d_in[4];
  const int*   adj1    = (const int*)d_in[5];
  const int*   pool0   = (const int*)d_in[6];
  const int*   pool1   = (const int*)d_in[7];
  const float* w1      = (const float*)d_in[8];
  const float* b1      = (const float*)d_in[9];
  const float* w2      = (const float*)d_in[10];
  const float* b2      = (const float*)d_in[11];
  const float* w3      = (const float*)d_in[12];
  const float* b3      = (const float*)d_in[13];
  float* out  = (float*)d_out;
  float* wsf  = (float*)d_ws;

  // words: region0 (xT64 [N0][16w] = 5,242,880 / h3 alias) | h2 5,242,880 |
  // fidxM 3,932,160 | fidxP 983,040 | A12 245,760 | G 2,560 | wB1 512 |
  // wB 2,560 | w3t 3,200  -> ~62.7 MB
  float* h3b   = wsf;
  uint4* xT64  = (uint4*)wsf;                   // aliases h3, dead after k1
  unsigned short* h2b = (unsigned short*)(wsf + 5242880);
  int* fidxM   = (int*)(wsf + 2 * 5242880);
  int* fidxP   = fidxM + (size_t)N1 * 4 * 12;
  float* A12   = (float*)(fidxP + (size_t)N2 * 4 * 12);
  float* G     = A12 + (size_t)N2 * 12;
  unsigned short* wB1 = (unsigned short*)(G + 2560);
  unsigned short* wB  = wB1 + 1024;
  float* w3t   = (float*)(wB + 5120);

  hipMemsetAsync(A12, 0, (size_t)(N2 * 12 + 2560) * 4, stream);  // A12 + G
  kpre<<<3380, 256, 0, stream>>>(x, xT64, conv_t0, conv_t1, conv_t2,
                                 adj0, adj1, pool0, pool1,
                                 fidxM, fidxP, A12,
                                 w1, w2, w3, b3, wB1, wB, w3t, out);
  k1<<<1280, 256, 0, stream>>>((const char*)xT64, fidxM, (const bf16x8*)wB1, b1, h2b);
  k2<<<1280, 256, 0, stream>>>((const char*)h2b, fidxP, (const bf16x8*)wB, b2, h3b);
  k3b<<<8 * (N2 / K3B_NCH), 256, 0, stream>>>(h3b, A12, G);
  k3c<<<10, 256, 0, stream>>>(G, w3t, out);
}

// Round 13
// 140.525 us; speedup vs baseline: 19.0524x; 1.1001x over previous
//
#include <hip/hip_runtime.h>

#define NB 8
#define CIN 3
#define N0 327680
#define N1 81920
#define N2 20480
#define KC 10
#define KA 4

typedef __attribute__((ext_vector_type(8))) short bf16x8;
typedef __attribute__((ext_vector_type(4))) float f32x4;
typedef int4  __attribute__((aligned(4))) int4_u;

__device__ __forceinline__ unsigned f2bf(float f) {          // RNE float->bf16
  unsigned u = __float_as_uint(f);
  return (u + 0x7FFFu + ((u >> 16) & 1u)) >> 16;
}

union bfrag { bf16x8 v; unsigned u[4]; };

// ---- fused prep: blocks [0,1280) transx | [1280,2560) fidx | [2560,3360) hist |
// [3360,3380) weight-prep.  A12/G zeroed by hipMemsetAsync beforehand. ----
__global__ __launch_bounds__(256) void kpre(
    const float* __restrict__ x, uint4* __restrict__ xT64,
    const int* __restrict__ conv_t0, const int* __restrict__ conv_t1,
    const int* __restrict__ conv_t2,
    const int* __restrict__ adj0, const int* __restrict__ adj1,
    const int* __restrict__ pool0, const int* __restrict__ pool1,
    int* __restrict__ fidxM, int* __restrict__ fidxP, float* __restrict__ A12,
    const float* __restrict__ w1, const float* __restrict__ w2,
    const float* __restrict__ w3, const float* __restrict__ b3,
    unsigned short* __restrict__ wB1, unsigned short* __restrict__ wB,
    float* __restrict__ w3t, float* __restrict__ out) {
  int blk = blockIdx.x;
  if (blk < 1280) {
    // ---- x -> xT64 [n][64B]: 4 bpair-triples {c0|c1, c2|c0', c1'|c2'} + 16B pad ----
    int n = blk * 256 + threadIdx.x;
    unsigned d[12];
#pragma unroll
    for (int bp = 0; bp < 4; ++bp) {
      const float* pe = x + (size_t)(2 * bp) * CIN * N0 + n;       // even batch
      const float* po = pe + (size_t)CIN * N0;                    // odd batch
      float e0 = pe[0], e1 = pe[N0], e2 = pe[2 * N0];
      float o0 = po[0], o1 = po[N0], o2 = po[2 * N0];
      d[bp * 3 + 0] = f2bf(e0) | (f2bf(e1) << 16);
      d[bp * 3 + 1] = f2bf(e2) | (f2bf(o0) << 16);
      d[bp * 3 + 2] = f2bf(o1) | (f2bf(o2) << 16);
    }
    uint4* dst = xT64 + (size_t)n * 4;
    dst[0] = make_uint4(d[0], d[1], d[2], d[3]);
    dst[1] = make_uint4(d[4], d[5], d[6], d[7]);
    dst[2] = make_uint4(d[8], d[9], d[10], d[11]);
    dst[3] = make_uint4(0, 0, 0, 0);
  } else if (blk < 2560) {
    // ---- index tables ----
    // fidxM row (48B): [t0 t1 t8 t9 | t2 t3 t4 t5 | t6 t7 0 0]  (byte offs, x64)
    // fidxP row (48B): [e0 e2 e4 e6 | e8 0 o1 o3 | o5 o7 o9 0]  (byte offs, x32)
    int t = (blk - 1280) * 256 + threadIdx.x;   // N1*4 threads
    int j = t >> 2, p = t & 3;
    int pj = pool0[j];
    int pos = adj0[pj * KA + p];
    const int2* s0 = (const int2*)(conv_t0 + (size_t)pos * 10);
    int2 q0 = s0[0], q1 = s0[1], q2 = s0[2], q3 = s0[3], q4 = s0[4];
    int4_u* dM = (int4_u*)(fidxM + (size_t)t * 12);
    dM[0] = make_int4(q0.x * 64, q0.y * 64, q4.x * 64, q4.y * 64);
    dM[1] = make_int4(q1.x * 64, q1.y * 64, q2.x * 64, q2.y * 64);
    dM[2] = make_int4(q3.x * 64, q3.y * 64, 0, 0);
    if (j < N2) {
      int qj = pool1[j];
      int qos = adj1[qj * KA + p];
      const int2* s1 = (const int2*)(conv_t1 + (size_t)qos * 10);
      int2 r0 = s1[0], r1 = s1[1], r2 = s1[2], r3 = s1[3], r4 = s1[4];
      int4_u* dP = (int4_u*)(fidxP + (size_t)t * 12);
      dP[0] = make_int4(r0.x * 32, r1.x * 32, r2.x * 32, r3.x * 32);
      dP[1] = make_int4(r4.x * 32, 0,          r0.y * 32, r1.y * 32);
      dP[2] = make_int4(r2.y * 32, r3.y * 32, r4.y * 32, 0);
    }
  } else if (blk < 3360) {
    // ---- histogram A[n][k] = #{j: conv_t2[j,k] = n} ----
    int t = (blk - 2560) * 256 + threadIdx.x;   // N2*10 threads
    int n = conv_t2[t];
    int k = t % 10;
    atomicAdd(&A12[n * 12 + k], 1.0f);
  } else {
    // ---- weight prep ----
    int t = (blk - 3360) * 256 + threadIdx.x;
    if (t < 1024) {
      int ch = t >> 9, rest = t & 511, l = rest >> 3, e = rest & 7;
      int k = ch * 32 + ((l >> 4) * 8) + e;
      int tap = k >> 2, cc = k & 3;
      float v = (tap < KC && cc < CIN) ? w1[((l & 15) * CIN + cc) * KC + tap] : 0.f;
      wB1[t] = (unsigned short)f2bf(v);
    }
    if (t < 5120) {
      int e = t & 7, l = (t >> 3) & 63, nt = (t >> 9) & 1, q = t >> 10;
      int kc = q * 32 + ((l >> 4) * 8) + e;
      int tap = kc >> 4, c = kc & 15;
      int o = nt * 16 + (l & 15);
      wB[t] = (unsigned short)f2bf(w2[(o * 16 + c) * KC + tap]);
    }
    if (t < 3200) { int o = t % 10, r = t / 10, c = r & 31, k = r >> 5;
                    w3t[t] = w3[(o * 32 + c) * KC + k]; }
    if (t < 80)   out[t] = b3[t % 10];
  }
}

// dword triple of bpair s (s compile-time) from a 12-dword row (Ra,Rb,Rc)
#define TR0(s) ((s) == 0 ? Ra.x : (s) == 1 ? Ra.w : (s) == 2 ? Rb.z : Rc.y)
#define TR1(s) ((s) == 0 ? Ra.y : (s) == 1 ? Rb.x : (s) == 2 ? Rb.w : Rc.z)
#define TR2(s) ((s) == 0 ? Ra.z : (s) == 1 ? Rb.y : (s) == 2 ? Rc.x : Rc.w)

// ---- conv1 (3->16) + maxpool0 via MFMA gather-GEMM. 1 tile/wave for max
// outstanding misses; hi>=1 lanes skip the taps-8/9 loads (B1 rows zero). ----
__global__ __launch_bounds__(256, 4) void k1(
    const char* __restrict__ xT64, const int* __restrict__ fidxM,
    const bf16x8* __restrict__ wB1, const float* __restrict__ b1,
    unsigned short* __restrict__ h2) {
  int blk = blockIdx.x;                         // 5120 blocks x 4 waves = 20480 tiles
  int wave = threadIdx.x >> 6;
  int lane = threadIdx.x & 63;
  int col = lane & 15, hi = lane >> 4;
  int tile = blk * 4 + wave;
  bf16x8 B0 = wB1[lane];
  bf16x8 B1 = wB1[64 + lane];
  float bias = b1[col];
  int seloff = ((hi + 1) >> 1) << 2;            // ints: hi->{0,4,4,8}

  int4 I = *(const int4_u*)(fidxM + ((size_t)tile * 16 + col) * 12 + seloff);
  int a0 = (hi == 2) ? I.z : I.x;               // tap 2hi
  int a1 = (hi == 2) ? I.w : I.y;               // tap 2hi+1
  const uint4* r0p = (const uint4*)(xT64 + a0);
  const uint4* r1p = (const uint4*)(xT64 + a1);
  uint4 R0a = r0p[0], R0b = r0p[1], R0c = r0p[2];
  uint4 R1a = r1p[0], R1b = r1p[1], R1c = r1p[2];
  uint4 zz = make_uint4(0, 0, 0, 0);
  uint4 R2a = zz, R2b = zz, R2c = zz, R3a = zz, R3b = zz, R3c = zz;
  if (hi == 0) {                                // taps 8,9 real only for hi=0
    const uint4* r2p = (const uint4*)(xT64 + I.z);
    const uint4* r3p = (const uint4*)(xT64 + I.w);
    R2a = r2p[0]; R2b = r2p[1]; R2c = r2p[2];
    R3a = r3p[0]; R3b = r3p[1]; R3c = r3p[2];
  }
  size_t j = (size_t)tile * 4 + hi;
  unsigned short* dst = h2 + j * 16 + col;

#define DO_BPAIR(s)                                                           \
  {                                                                           \
    unsigned t0, t1, t2, u0, u1, u2, v0, v1, v2, w0, w1, w2;                  \
    { uint4 Ra = R0a, Rb = R0b, Rc = R0c;                                     \
      t0 = TR0(s); t1 = TR1(s); t2 = TR2(s); }                                \
    { uint4 Ra = R1a, Rb = R1b, Rc = R1c;                                     \
      u0 = TR0(s); u1 = TR1(s); u2 = TR2(s); }                                \
    { uint4 Ra = R2a, Rb = R2b, Rc = R2c;                                     \
      v0 = TR0(s); v1 = TR1(s); v2 = TR2(s); }                                \
    { uint4 Ra = R3a, Rb = R3b, Rc = R3c;                                     \
      w0 = TR0(s); w1 = TR1(s); w2 = TR2(s); }                                \
    bfrag A0c0, A1c0, A0c1, A1c1;                                             \
    A0c0.u[0] = t0; A0c0.u[1] = t1 & 0xFFFFu;                                 \
    A0c0.u[2] = u0; A0c0.u[3] = u1 & 0xFFFFu;                                 \
    A1c0.u[0] = (t1 >> 16) | (t2 << 16); A1c0.u[1] = t2 >> 16;                \
    A1c0.u[2] = (u1 >> 16) | (u2 << 16); A1c0.u[3] = u2 >> 16;                \
    A0c1.u[0] = v0; A0c1.u[1] = v1 & 0xFFFFu;                                 \
    A0c1.u[2] = w0; A0c1.u[3] = w1 & 0xFFFFu;                                 \
    A1c1.u[0] = (v1 >> 16) | (v2 << 16); A1c1.u[1] = v2 >> 16;                \
    A1c1.u[2] = (w1 >> 16) | (w2 << 16); A1c1.u[3] = w2 >> 16;                \
    f32x4 z = {0.f, 0.f, 0.f, 0.f};                                           \
    f32x4 acc0 = __builtin_amdgcn_mfma_f32_16x16x32_bf16(A0c0.v, B0, z, 0, 0, 0); \
    acc0 = __builtin_amdgcn_mfma_f32_16x16x32_bf16(A0c1.v, B1, acc0, 0, 0, 0);    \
    f32x4 acc1 = __builtin_amdgcn_mfma_f32_16x16x32_bf16(A1c0.v, B0, z, 0, 0, 0); \
    acc1 = __builtin_amdgcn_mfma_f32_16x16x32_bf16(A1c1.v, B1, acc1, 0, 0, 0);    \
    float m0 = fmaxf(fmaxf(acc0[0], acc0[1]), fmaxf(acc0[2], acc0[3])) + bias;    \
    float m1 = fmaxf(fmaxf(acc1[0], acc1[1]), fmaxf(acc1[2], acc1[3])) + bias;    \
    dst[(size_t)(2 * (s)) * N1 * 16]     = (unsigned short)f2bf(m0);          \
    dst[(size_t)(2 * (s) + 1) * N1 * 16] = (unsigned short)f2bf(m1);          \
  }
  DO_BPAIR(0)
  DO_BPAIR(1)
  DO_BPAIR(2)
  DO_BPAIR(3)
#undef DO_BPAIR
}

// ---- conv2 (16->32) + maxpool1 via MFMA gather-GEMM; 2 idx + 5 gathers per tile ----
__global__ __launch_bounds__(256) void k2(
    const char* __restrict__ h2, const int* __restrict__ fidxP,
    const bf16x8* __restrict__ wB, const float* __restrict__ b2,
    float* __restrict__ h3) {
  int blk = blockIdx.x;
  int b = blk & 7;
  int wave = threadIdx.x >> 6;
  int lane = threadIdx.x & 63;
  int col = lane & 15;
  int odd = (lane >> 5) & 1;
  int tile0 = ((blk >> 3) * 4 + wave) * 8;
  const char* hb = h2 + (size_t)b * N1 * 32 + ((lane >> 4) & 1) * 16;

  bf16x8 Bf[10];
#pragma unroll
  for (int i = 0; i < 10; ++i) Bf[i] = wB[i * 64 + lane];
  float bias0 = b2[col];
  float bias1 = b2[16 + col];

#pragma unroll 2
  for (int i = 0; i < 8; ++i) {
    int tile = tile0 + i;
    const int* fp = fidxP + ((size_t)tile * 16 + col) * 12 + odd * 6;
    int4 T = *(const int4_u*)fp;                // 4 taps of my parity
    int  T4 = fp[4];                            // 5th tap
    f32x4 acc0 = {0.f, 0.f, 0.f, 0.f};
    f32x4 acc1 = {0.f, 0.f, 0.f, 0.f};
    bf16x8 A;
    A = *(const bf16x8*)(hb + T.x);
    acc0 = __builtin_amdgcn_mfma_f32_16x16x32_bf16(A, Bf[0], acc0, 0, 0, 0);
    acc1 = __builtin_amdgcn_mfma_f32_16x16x32_bf16(A, Bf[1], acc1, 0, 0, 0);
    A = *(const bf16x8*)(hb + T.y);
    acc0 = __builtin_amdgcn_mfma_f32_16x16x32_bf16(A, Bf[2], acc0, 0, 0, 0);
    acc1 = __builtin_amdgcn_mfma_f32_16x16x32_bf16(A, Bf[3], acc1, 0, 0, 0);
    A = *(const bf16x8*)(hb + T.z);
    acc0 = __builtin_amdgcn_mfma_f32_16x16x32_bf16(A, Bf[4], acc0, 0, 0, 0);
    acc1 = __builtin_amdgcn_mfma_f32_16x16x32_bf16(A, Bf[5], acc1, 0, 0, 0);
    A = *(const bf16x8*)(hb + T.w);
    acc0 = __builtin_amdgcn_mfma_f32_16x16x32_bf16(A, Bf[6], acc0, 0, 0, 0);
    acc1 = __builtin_amdgcn_mfma_f32_16x16x32_bf16(A, Bf[7], acc1, 0, 0, 0);
    A = *(const bf16x8*)(hb + T4);
    acc0 = __builtin_amdgcn_mfma_f32_16x16x32_bf16(A, Bf[8], acc0, 0, 0, 0);
    acc1 = __builtin_amdgcn_mfma_f32_16x16x32_bf16(A, Bf[9], acc1, 0, 0, 0);
    float m0 = fmaxf(fmaxf(acc0[0], acc0[1]), fmaxf(acc0[2], acc0[3])) + bias0;
    float m1 = fmaxf(fmaxf(acc1[0], acc1[1]), fmaxf(acc1[2], acc1[3])) + bias1;
    int j = tile * 4 + (lane >> 4);
    float* dst = h3 + ((size_t)b * N2 + j) * 32 + col;
    dst[0]  = m0;
    dst[16] = m1;
  }
}

// ---- G[b][c][k] = sum_n A[n][k] * h3[b][n][c] : sequential h3 stream ----
#define K3B_NCH 256
__global__ __launch_bounds__(256) void k3b(
    const float* __restrict__ h3, const float* __restrict__ A12,
    float* __restrict__ G) {
  __shared__ float SA[K3B_NCH * 12];
  __shared__ float GL[320];
  int blk = blockIdx.x;                         // 8 b x 80 chunks
  int b = blk & 7;
  int n0 = (blk >> 3) * K3B_NCH;
  int tid = threadIdx.x;
  const float4* src = (const float4*)(A12 + (size_t)n0 * 12);
#pragma unroll
  for (int i = 0; i < 3; ++i)
    ((float4*)SA)[tid + i * 256] = src[tid + i * 256];
  for (int i = tid; i < 320; i += 256) GL[i] = 0.f;
  __syncthreads();
  int wave = tid >> 6, lane = tid & 63;
  int c = lane & 31, nh = lane >> 5;
  float acc[10];
#pragma unroll
  for (int o = 0; o < 10; ++o) acc[o] = 0.f;
#pragma unroll 4
  for (int s = 0; s < K3B_NCH / 8; ++s) {
    int nl = s * 8 + wave * 2 + nh;
    float hv = h3[((size_t)b * N2 + n0 + nl) * 32 + c];
    const float4* ar = (const float4*)(SA + nl * 12);
    float4 a0 = ar[0], a1 = ar[1], a2 = ar[2];
    acc[0] += hv * a0.x; acc[1] += hv * a0.y;
    acc[2] += hv * a0.z; acc[3] += hv * a0.w;
    acc[4] += hv * a1.x; acc[5] += hv * a1.y;
    acc[6] += hv * a1.z; acc[7] += hv * a1.w;
    acc[8] += hv * a2.x; acc[9] += hv * a2.y;
  }
#pragma unroll
  for (int o = 0; o < 10; ++o) acc[o] += __shfl_xor(acc[o], 32);
  if (lane < 32) {
#pragma unroll
    for (int o = 0; o < 10; ++o) atomicAdd(&GL[c * 10 + o], acc[o]);
  }
  __syncthreads();
  for (int i = tid; i < 320; i += 256)
    atomicAdd(&G[b * 320 + i], GL[i]);
}

// ---- out[b][o] += (1/N2) * sum_{c,k} w3t[k][c][o] * G[b][c][k] ----
__global__ __launch_bounds__(256) void k3c(
    const float* __restrict__ G, const float* __restrict__ w3t,
    float* __restrict__ out) {
  int t = blockIdx.x * 256 + threadIdx.x;       // 2560 threads
  int pair = t >> 5, c = t & 31;
  int b = pair / 10, o = pair % 10;
  float s = 0.f;
#pragma unroll
  for (int k = 0; k < KC; ++k)
    s += G[b * 320 + c * 10 + k] * w3t[k * 320 + c * 10 + o];
#pragma unroll
  for (int off = 1; off < 32; off <<= 1) s += __shfl_xor(s, off);
  if ((threadIdx.x & 31) == 0) atomicAdd(&out[pair], s * (1.0f / N2));
}

extern "C" void kernel_launch(void* const* d_in, const int* in_sizes, int n_in,
                              void* d_out, int out_size, void* d_ws, size_t ws_size,
                              hipStream_t stream) {
  const float* x       = (const float*)d_in[0];
  const int*   conv_t0 = (const int*)d_in[1];
  const int*   conv_t1 = (const int*)d_in[2];
  const int*   conv_t2 = (const int*)d_in[3];
  const int*   adj0    = (const int*)d_in[4];
  const int*   adj1    = (const int*)d_in[5];
  const int*   pool0   = (const int*)d_in[6];
  const int*   pool1   = (const int*)d_in[7];
  const float* w1      = (const float*)d_in[8];
  const float* b1      = (const float*)d_in[9];
  const float* w2      = (const float*)d_in[10];
  const float* b2      = (const float*)d_in[11];
  const float* w3      = (const float*)d_in[12];
  const float* b3      = (const float*)d_in[13];
  float* out  = (float*)d_out;
  float* wsf  = (float*)d_ws;

  // words: region0 (xT64 [N0][16w] = 5,242,880 / h3 alias) | h2 5,242,880 |
  // fidxM 3,932,160 | fidxP 983,040 | A12 245,760 | G 2,560 | wB1 512 |
  // wB 2,560 | w3t 3,200  -> ~62.7 MB
  float* h3b   = wsf;
  uint4* xT64  = (uint4*)wsf;                   // aliases h3, dead after k1
  unsigned short* h2b = (unsigned short*)(wsf + 5242880);
  int* fidxM   = (int*)(wsf + 2 * 5242880);
  int* fidxP   = fidxM + (size_t)N1 * 4 * 12;
  float* A12   = (float*)(fidxP + (size_t)N2 * 4 * 12);
  float* G     = A12 + (size_t)N2 * 12;
  unsigned short* wB1 = (unsigned short*)(G + 2560);
  unsigned short* wB  = wB1 + 1024;
  float* w3t   = (float*)(wB + 5120);

  hipMemsetAsync(A12, 0, (size_t)(N2 * 12 + 2560) * 4, stream);  // A12 + G
  kpre<<<3380, 256, 0, stream>>>(x, xT64, conv_t0, conv_t1, conv_t2,
                                 adj0, adj1, pool0, pool1,
                                 fidxM, fidxP, A12,
                                 w1, w2, w3, b3, wB1, wB, w3t, out);
  k1<<<5120, 256, 0, stream>>>((const char*)xT64, fidxM, (const bf16x8*)wB1, b1, h2b);
  k2<<<1280, 256, 0, stream>>>((const char*)h2b, fidxP, (const bf16x8*)wB, b2, h3b);
  k3b<<<8 * (N2 / K3B_NCH), 256, 0, stream>>>(h3b, A12, G);
  k3c<<<10, 256, 0, stream>>>(G, w3t, out);
}